// Round 2
// baseline (8449.046 us; speedup 1.0000x reference)
//
#include <hip/hip_runtime.h>
#include <math.h>

#define NB 4
#define NSEQ 8192
#define DMODEL 512
#define NHEADS 8
#define DHEAD 64
#define NLM 256
#define LTOK 32
#define NBH 32
#define KCONV 33

typedef unsigned short bf16_t;

__device__ __forceinline__ float bf2f(bf16_t u) {
  return __uint_as_float(((unsigned)u) << 16);
}
__device__ __forceinline__ bf16_t f2bf(float f) {
  unsigned u = __float_as_uint(f);
  return (bf16_t)((u + 0x7fffu + ((u >> 16) & 1u)) >> 16);  // RTNE
}
// unpack a uint32 holding 2 bf16 (little-endian: elem0 = low 16 bits)
__device__ __forceinline__ void bfpair(unsigned u, float& lo, float& hi) {
  lo = __uint_as_float(u << 16);
  hi = __uint_as_float(u & 0xffff0000u);
}

// ---------------- LayerNorm: one wave per 512-float row, bf16 out ----------------
__global__ __launch_bounds__(256) void ln_kernel(const float* __restrict__ x,
    const float* __restrict__ gamma, const float* __restrict__ beta,
    bf16_t* __restrict__ xn) {
  int row = blockIdx.x * 4 + (threadIdx.x >> 6);
  int lane = threadIdx.x & 63;
  const float4* xr = reinterpret_cast<const float4*>(x + (size_t)row * DMODEL);
  float4 a0 = xr[lane];
  float4 a1 = xr[lane + 64];
  float s  = a0.x + a0.y + a0.z + a0.w + a1.x + a1.y + a1.z + a1.w;
  float s2 = a0.x*a0.x + a0.y*a0.y + a0.z*a0.z + a0.w*a0.w
           + a1.x*a1.x + a1.y*a1.y + a1.z*a1.z + a1.w*a1.w;
  #pragma unroll
  for (int off = 32; off; off >>= 1) {
    s  += __shfl_down(s, off);
    s2 += __shfl_down(s2, off);
  }
  s = __shfl(s, 0); s2 = __shfl(s2, 0);
  float mu = s * (1.0f / DMODEL);
  float var = s2 * (1.0f / DMODEL) - mu * mu;
  float rs = rsqrtf(var + 1e-5f);
  const float4* g4 = reinterpret_cast<const float4*>(gamma);
  const float4* b4 = reinterpret_cast<const float4*>(beta);
  float4 g0 = g4[lane], g1 = g4[lane + 64];
  float4 bb0 = b4[lane], bb1 = b4[lane + 64];
  ushort4 o0, o1;
  o0.x = f2bf((a0.x - mu) * rs * g0.x + bb0.x);
  o0.y = f2bf((a0.y - mu) * rs * g0.y + bb0.y);
  o0.z = f2bf((a0.z - mu) * rs * g0.z + bb0.z);
  o0.w = f2bf((a0.w - mu) * rs * g0.w + bb0.w);
  o1.x = f2bf((a1.x - mu) * rs * g1.x + bb1.x);
  o1.y = f2bf((a1.y - mu) * rs * g1.y + bb1.y);
  o1.z = f2bf((a1.z - mu) * rs * g1.z + bb1.z);
  o1.w = f2bf((a1.w - mu) * rs * g1.w + bb1.w);
  ushort4* o = reinterpret_cast<ushort4*>(xn + (size_t)row * DMODEL);
  o[lane] = o0; o[lane + 64] = o1;
}

// ---------------- QKV GEMM: (32768x512)@(512x1536), bf16 A in, bf16 qkv out ----------------
__global__ __launch_bounds__(256) void gemm_qkv(const bf16_t* __restrict__ A,
    const float* __restrict__ Bm, bf16_t* __restrict__ q, bf16_t* __restrict__ k,
    bf16_t* __restrict__ v) {
  __shared__ float As[16][65];
  __shared__ float Bs[16][64];
  int rowB = blockIdx.x * 64, colB = blockIdx.y * 64;
  int tid = threadIdx.x, tx = tid & 15, ty = tid >> 4;
  float acc[4][4] = {};
  for (int k0 = 0; k0 < DMODEL; k0 += 16) {
    {
      int row = tid >> 2, quad = tid & 3;  // 64 rows x 4 quads of 4 bf16
      const ushort4 a4 = *reinterpret_cast<const ushort4*>(
          A + (size_t)(rowB + row) * DMODEL + k0 + quad * 4);
      As[quad * 4 + 0][row] = bf2f(a4.x);
      As[quad * 4 + 1][row] = bf2f(a4.y);
      As[quad * 4 + 2][row] = bf2f(a4.z);
      As[quad * 4 + 3][row] = bf2f(a4.w);
    }
    #pragma unroll
    for (int i = 0; i < 4; ++i) {
      int idx = tid + i * 256;
      Bs[idx >> 6][idx & 63] = Bm[(size_t)(k0 + (idx >> 6)) * 1536 + colB + (idx & 63)];
    }
    __syncthreads();
    #pragma unroll
    for (int kk = 0; kk < 16; ++kk) {
      float av[4], bv[4];
      #pragma unroll
      for (int i = 0; i < 4; ++i) av[i] = As[kk][ty + 16 * i];
      #pragma unroll
      for (int j = 0; j < 4; ++j) bv[j] = Bs[kk][tx + 16 * j];
      #pragma unroll
      for (int i = 0; i < 4; ++i)
        #pragma unroll
        for (int j = 0; j < 4; ++j) acc[i][j] += av[i] * bv[j];
    }
    __syncthreads();
  }
  #pragma unroll
  for (int i = 0; i < 4; ++i) {
    int r = rowB + ty + 16 * i;
    int b = r >> 13, n = r & 8191;
    #pragma unroll
    for (int j = 0; j < 4; ++j) {
      int c = colB + tx + 16 * j;
      int which = c >> 9, hc = c & 511, h = hc >> 6, d = hc & 63;
      float val = acc[i][j];
      bf16_t* dst = (which == 0) ? q : (which == 1 ? k : v);
      if (which == 0) val *= 0.125f;  // dh^-0.5
      dst[((size_t)(b * NHEADS + h) * NSEQ + n) * DHEAD + d] = f2bf(val);
    }
  }
}

// ---------------- landmark mean pooling (q and k), fp32 out ----------------
__global__ void pool_kernel(const bf16_t* __restrict__ q, const bf16_t* __restrict__ k,
                            float* __restrict__ ql, float* __restrict__ kl) {
  int idx = blockIdx.x * 256 + threadIdx.x;  // 2 * 524288
  const int half = NBH * NLM * DHEAD;
  const bf16_t* src = (idx < half) ? q : k;
  float* dst = (idx < half) ? ql : kl;
  int i = (idx < half) ? idx : idx - half;
  int d = i & 63, m = (i >> 6) & 255, bh = i >> 14;
  const bf16_t* p = src + ((size_t)bh * NSEQ + m * LTOK) * DHEAD + d;
  float sum = 0.f;
  #pragma unroll
  for (int t = 0; t < LTOK; ++t) sum += bf2f(p[(size_t)t * DHEAD]);
  dst[i] = sum * (1.0f / LTOK);
}

// ---------------- attn2 = softmax(q_l @ k_l^T), 256x256 per bh ----------------
__global__ __launch_bounds__(256) void attn2_kernel(const float* __restrict__ ql,
    const float* __restrict__ kl, float* __restrict__ a2) {
  __shared__ float qs[64];
  __shared__ float red[256];
  int bh = blockIdx.y, i = blockIdx.x, t = threadIdx.x;
  if (t < 64) qs[t] = ql[((size_t)bh * NLM + i) * DHEAD + t];
  __syncthreads();
  const float* kr = kl + ((size_t)bh * NLM + t) * DHEAD;
  float s = 0.f;
  #pragma unroll
  for (int d = 0; d < 64; ++d) s += qs[d] * kr[d];
  red[t] = s; __syncthreads();
  for (int off = 128; off; off >>= 1) { if (t < off) red[t] = fmaxf(red[t], red[t + off]); __syncthreads(); }
  float mx = red[0]; __syncthreads();
  float p = expf(s - mx);
  red[t] = p; __syncthreads();
  for (int off = 128; off; off >>= 1) { if (t < off) red[t] += red[t + off]; __syncthreads(); }
  a2[((size_t)bh * NLM + i) * NLM + t] = p / red[0];
}

__global__ void zero2_kernel(unsigned int* __restrict__ scal) {
  if (threadIdx.x < 2) scal[threadIdx.x] = 0u;
}

// ---------------- global col/row maxima for pinv init ----------------
__global__ void colrow_kernel(const float* __restrict__ a2, unsigned int* __restrict__ scal) {
  int bh = blockIdx.x & 31, mode = blockIdx.x >> 5;
  int t = threadIdx.x;
  const float* Ab = a2 + (size_t)bh * NLM * NLM;
  float sum = 0.f;
  if (mode == 0) { for (int j = 0; j < NLM; ++j) sum += fabsf(Ab[(size_t)t * NLM + j]); }
  else           { for (int i2 = 0; i2 < NLM; ++i2) sum += fabsf(Ab[(size_t)i2 * NLM + t]); }
  __shared__ float red[256];
  red[t] = sum; __syncthreads();
  for (int off = 128; off; off >>= 1) { if (t < off) red[t] = fmaxf(red[t], red[t + off]); __syncthreads(); }
  if (t == 0) atomicMax(&scal[mode], __float_as_uint(red[0]));  // all values > 0
}

// ---------------- z0 = a^T / (col*row) ----------------
__global__ void zinit_kernel(const float* __restrict__ a2, const unsigned int* __restrict__ scal,
                             float* __restrict__ z) {
  int idx = blockIdx.x * 256 + threadIdx.x;  // 2097152
  float inv = 1.0f / (__uint_as_float(scal[0]) * __uint_as_float(scal[1]));
  int j = idx & 255, i = (idx >> 8) & 255, bh = idx >> 16;
  z[idx] = a2[((size_t)bh * NLM + j) * NLM + i] * inv;
}

// ---------------- batched 256x256 matmul: C = alpha*(s*A - A@B) per bh ----------------
__global__ __launch_bounds__(256) void matmul256(float* __restrict__ C,
    const float* __restrict__ A, const float* __restrict__ Bm, float s, float alpha) {
  __shared__ float As[16][65];
  __shared__ float Bs[16][64];
  int bh = blockIdx.y;
  const float* Ab = A + (size_t)bh * NLM * NLM;
  const float* Bb = Bm + (size_t)bh * NLM * NLM;
  float* Cb = C + (size_t)bh * NLM * NLM;
  int rowB = (blockIdx.x >> 2) * 64, colB = (blockIdx.x & 3) * 64;
  int tid = threadIdx.x, tx = tid & 15, ty = tid >> 4;
  float acc[4][4] = {};
  for (int k0 = 0; k0 < NLM; k0 += 16) {
    #pragma unroll
    for (int i = 0; i < 4; ++i) {
      int idx = tid + i * 256;
      As[idx & 15][idx >> 4] = Ab[(size_t)(rowB + (idx >> 4)) * NLM + k0 + (idx & 15)];
    }
    #pragma unroll
    for (int i = 0; i < 4; ++i) {
      int idx = tid + i * 256;
      Bs[idx >> 6][idx & 63] = Bb[(size_t)(k0 + (idx >> 6)) * NLM + colB + (idx & 63)];
    }
    __syncthreads();
    #pragma unroll
    for (int kk = 0; kk < 16; ++kk) {
      float av[4], bv[4];
      #pragma unroll
      for (int i = 0; i < 4; ++i) av[i] = As[kk][ty + 16 * i];
      #pragma unroll
      for (int j = 0; j < 4; ++j) bv[j] = Bs[kk][tx + 16 * j];
      #pragma unroll
      for (int i = 0; i < 4; ++i)
        #pragma unroll
        for (int j = 0; j < 4; ++j) acc[i][j] += av[i] * bv[j];
    }
    __syncthreads();
  }
  #pragma unroll
  for (int i = 0; i < 4; ++i) {
    int r = rowB + ty + 16 * i;
    #pragma unroll
    for (int j = 0; j < 4; ++j) {
      int c = colB + tx + 16 * j;
      float aij = (s != 0.0f) ? Ab[(size_t)r * NLM + c] : 0.0f;
      Cb[(size_t)r * NLM + c] = alpha * (s * aij - acc[i][j]);
    }
  }
}

// ---------------- W = softmax(q_l @ k^T) @ v : one block per (bh, landmark) ----------------
__global__ __launch_bounds__(256) void attn3v_kernel(const float* __restrict__ ql,
    const bf16_t* __restrict__ k, const bf16_t* __restrict__ v, float* __restrict__ W) {
  __shared__ float qs[64];
  __shared__ float sl[NSEQ];
  __shared__ float red[256];
  int bh = blockIdx.y, i = blockIdx.x, t = threadIdx.x;
  if (t < 64) qs[t] = ql[((size_t)bh * NLM + i) * DHEAD + t];
  __syncthreads();
  const bf16_t* kb = k + (size_t)bh * NSEQ * DHEAD;
  float lmax = -1e30f;
  for (int j = t; j < NSEQ; j += 256) {
    const uint4* kr = reinterpret_cast<const uint4*>(kb + (size_t)j * DHEAD);
    float s = 0.f;
    #pragma unroll
    for (int c = 0; c < 4; ++c) {
      uint4 kv = kr[c];
      float f0, f1;
      bfpair(kv.x, f0, f1); s += qs[c*8+0]*f0 + qs[c*8+1]*f1;
      bfpair(kv.y, f0, f1); s += qs[c*8+2]*f0 + qs[c*8+3]*f1;
      bfpair(kv.z, f0, f1); s += qs[c*8+4]*f0 + qs[c*8+5]*f1;
      bfpair(kv.w, f0, f1); s += qs[c*8+6]*f0 + qs[c*8+7]*f1;
    }
    sl[j] = s;
    lmax = fmaxf(lmax, s);
  }
  red[t] = lmax; __syncthreads();
  for (int off = 128; off; off >>= 1) { if (t < off) red[t] = fmaxf(red[t], red[t + off]); __syncthreads(); }
  float mx = red[0]; __syncthreads();
  float lsum = 0.f;
  for (int j = t; j < NSEQ; j += 256) { float p = expf(sl[j] - mx); sl[j] = p; lsum += p; }
  red[t] = lsum; __syncthreads();
  for (int off = 128; off; off >>= 1) { if (t < off) red[t] += red[t + off]; __syncthreads(); }
  float inv = 1.0f / red[0];
  __syncthreads();
  int d = t & 63, g = t >> 6;
  const bf16_t* vb = v + (size_t)bh * NSEQ * DHEAD + d;
  float acc = 0.f;
  for (int j = g * 2048; j < g * 2048 + 2048; ++j) acc += sl[j] * bf2f(vb[(size_t)j * DHEAD]);
  red[t] = acc; __syncthreads();
  if (t < 64)
    W[((size_t)bh * NLM + i) * DHEAD + t] = (red[t] + red[t + 64] + red[t + 128] + red[t + 192]) * inv;
}

// ---------------- U = Z @ W : (256x256)@(256x64) per bh ----------------
__global__ void zw_kernel(const float* __restrict__ z, const float* __restrict__ W,
                          float* __restrict__ U) {
  int idx = blockIdx.x * 256 + threadIdx.x;  // NBH*NLM*DHEAD
  int d = idx & 63, i = (idx >> 6) & 255, bh = idx >> 14;
  const float* zr = z + ((size_t)bh * NLM + i) * NLM;
  const float* Wb = W + (size_t)bh * NLM * DHEAD + d;
  float acc = 0.f;
  for (int j = 0; j < NLM; ++j) acc += zr[j] * Wb[(size_t)j * DHEAD];
  U[idx] = acc;
}

// ---------------- out = softmax(q @ k_l^T) @ U, k_l & U staged in LDS ----------------
__global__ __launch_bounds__(256, 1) void attn1_kernel(const bf16_t* __restrict__ q,
    const float* __restrict__ kl, const float* __restrict__ U, bf16_t* __restrict__ outp) {
  __shared__ float kls[NLM][65];
  __shared__ float Us[NLM][64];
  __shared__ float qs[4][64];
  __shared__ float ps[4][256];
  int bh = blockIdx.y, t = threadIdx.x;
  int w = t >> 6, lane = t & 63;
  const float* klb = kl + (size_t)bh * NLM * DHEAD;
  const float* Ub  = U  + (size_t)bh * NLM * DHEAD;
  for (int p = t; p < NLM * DHEAD; p += 256) {
    int r = p >> 6, c = p & 63;
    kls[r][c] = klb[p];
    Us[r][c]  = Ub[p];
  }
  __syncthreads();
  int b = bh >> 3, h = bh & 7;
  int q0 = blockIdx.x * 512;
  const bf16_t* qb = q + (size_t)bh * NSEQ * DHEAD;
  for (int qq = q0 + w; qq < q0 + 512; qq += 4) {
    qs[w][lane] = bf2f(qb[(size_t)qq * DHEAD + lane]);
    __syncthreads();
    float sc[4]; float mx = -1e30f;
    #pragma unroll
    for (int rr = 0; rr < 4; ++rr) {
      int j = lane + rr * 64;
      float s = 0.f;
      #pragma unroll
      for (int d = 0; d < 64; ++d) s += qs[w][d] * kls[j][d];
      sc[rr] = s; mx = fmaxf(mx, s);
    }
    #pragma unroll
    for (int off = 32; off; off >>= 1) mx = fmaxf(mx, __shfl_xor(mx, off));
    float lsum = 0.f;
    #pragma unroll
    for (int rr = 0; rr < 4; ++rr) { sc[rr] = expf(sc[rr] - mx); lsum += sc[rr]; }
    #pragma unroll
    for (int off = 32; off; off >>= 1) lsum += __shfl_xor(lsum, off);
    float inv = 1.0f / lsum;
    #pragma unroll
    for (int rr = 0; rr < 4; ++rr) ps[w][lane + rr * 64] = sc[rr] * inv;
    __syncthreads();
    float acc = 0.f;
    for (int j = 0; j < NLM; ++j) acc += ps[w][j] * Us[j][lane];
    outp[((size_t)(b * NSEQ + qq)) * DMODEL + h * DHEAD + lane] = f2bf(acc);
    __syncthreads();
  }
}

// ---------------- depthwise conv residual, added into bf16 out_pre ----------------
__global__ void conv_kernel(const bf16_t* __restrict__ v, const float* __restrict__ rk,
                            bf16_t* __restrict__ outp) {
  int idx = blockIdx.x * 256 + threadIdx.x;  // NB*NSEQ*DMODEL
  int d = idx & 63, h = (idx >> 6) & 7, n = (idx >> 9) & 8191, b = idx >> 22;
  const bf16_t* vb = v + ((size_t)(b * NHEADS + h) * NSEQ) * DHEAD + d;
  const float* wk = rk + h * KCONV;
  float acc = 0.f;
  #pragma unroll
  for (int tp = 0; tp < KCONV; ++tp) {
    int nn = n + tp - 16;
    if (nn >= 0 && nn < NSEQ) acc += bf2f(vb[(size_t)nn * DHEAD]) * wk[tp];
  }
  outp[idx] = f2bf(bf2f(outp[idx]) + acc);
}

// ---------------- final: y = x + out_pre @ w_out + b_out ----------------
__global__ __launch_bounds__(256) void gemm_out(const bf16_t* __restrict__ A,
    const float* __restrict__ Bm, const float* __restrict__ bo,
    const float* __restrict__ x, float* __restrict__ y) {
  __shared__ float As[16][65];
  __shared__ float Bs[16][64];
  int rowB = blockIdx.x * 64, colB = blockIdx.y * 64;
  int tid = threadIdx.x, tx = tid & 15, ty = tid >> 4;
  float acc[4][4] = {};
  for (int k0 = 0; k0 < DMODEL; k0 += 16) {
    {
      int row = tid >> 2, quad = tid & 3;
      const ushort4 a4 = *reinterpret_cast<const ushort4*>(
          A + (size_t)(rowB + row) * DMODEL + k0 + quad * 4);
      As[quad * 4 + 0][row] = bf2f(a4.x);
      As[quad * 4 + 1][row] = bf2f(a4.y);
      As[quad * 4 + 2][row] = bf2f(a4.z);
      As[quad * 4 + 3][row] = bf2f(a4.w);
    }
    #pragma unroll
    for (int i = 0; i < 4; ++i) {
      int idx = tid + i * 256;
      Bs[idx >> 6][idx & 63] = Bm[(size_t)(k0 + (idx >> 6)) * DMODEL + colB + (idx & 63)];
    }
    __syncthreads();
    #pragma unroll
    for (int kk = 0; kk < 16; ++kk) {
      float av[4], bv[4];
      #pragma unroll
      for (int i = 0; i < 4; ++i) av[i] = As[kk][ty + 16 * i];
      #pragma unroll
      for (int j = 0; j < 4; ++j) bv[j] = Bs[kk][tx + 16 * j];
      #pragma unroll
      for (int i = 0; i < 4; ++i)
        #pragma unroll
        for (int j = 0; j < 4; ++j) acc[i][j] += av[i] * bv[j];
    }
    __syncthreads();
  }
  #pragma unroll
  for (int i = 0; i < 4; ++i) {
    int r = rowB + ty + 16 * i;
    #pragma unroll
    for (int j = 0; j < 4; ++j) {
      int c = colB + tx + 16 * j;
      y[(size_t)r * DMODEL + c] = x[(size_t)r * DMODEL + c] + bo[c] + acc[i][j];
    }
  }
}

extern "C" void kernel_launch(void* const* d_in, const int* in_sizes, int n_in,
                              void* d_out, int out_size, void* d_ws, size_t ws_size,
                              hipStream_t stream) {
  const float* x     = (const float*)d_in[0];
  const float* gamma = (const float*)d_in[1];
  const float* beta  = (const float*)d_in[2];
  const float* wqkv  = (const float*)d_in[3];
  const float* wout  = (const float*)d_in[4];
  const float* bout  = (const float*)d_in[5];
  const float* rk    = (const float*)d_in[6];
  float* y = (float*)d_out;

  // ---- workspace layout: 176 MB + 8 B total ----
  char* wsb = (char*)d_ws;
  bf16_t* xn = (bf16_t*)(wsb);                   // 32 MB, reused as out_pre
  bf16_t* q  = (bf16_t*)(wsb + 33554432ull);     // 32 MB
  bf16_t* k  = (bf16_t*)(wsb + 67108864ull);     // 32 MB
  bf16_t* v  = (bf16_t*)(wsb + 100663296ull);    // 32 MB
  float* a2  = (float*)(wsb + 134217728ull);     // 8 MB
  float* z   = (float*)(wsb + 142606336ull);     // 8 MB
  float* az  = (float*)(wsb + 150994944ull);     // 8 MB
  float* t1  = (float*)(wsb + 159383552ull);     // 8 MB
  float* t2  = (float*)(wsb + 167772160ull);     // 8 MB
  float* ql  = (float*)(wsb + 176160768ull);     // 2 MB
  float* kl  = (float*)(wsb + 178257920ull);     // 2 MB
  float* Wm  = (float*)(wsb + 180355072ull);     // 2 MB
  float* Um  = (float*)(wsb + 182452224ull);     // 2 MB
  unsigned int* scal = (unsigned int*)(wsb + 184549376ull);  // 8 B

  ln_kernel<<<8192, 256, 0, stream>>>(x, gamma, beta, xn);
  gemm_qkv<<<dim3(512, 24), 256, 0, stream>>>(xn, wqkv, q, k, v);
  pool_kernel<<<4096, 256, 0, stream>>>(q, k, ql, kl);
  attn2_kernel<<<dim3(256, 32), 256, 0, stream>>>(ql, kl, a2);
  zero2_kernel<<<1, 64, 0, stream>>>(scal);
  colrow_kernel<<<64, 256, 0, stream>>>(a2, scal);
  zinit_kernel<<<8192, 256, 0, stream>>>(a2, scal, z);

  float *pz = z, *paz = az, *pt1 = t1, *pt2 = t2;
  for (int it = 0; it < 6; ++it) {
    matmul256<<<dim3(16, 32), 256, 0, stream>>>(paz, a2, pz, 0.f, -1.f);   // az = a@z
    matmul256<<<dim3(16, 32), 256, 0, stream>>>(pt2, paz, paz, 7.f, 1.f);  // t2 = 7*az - az@az
    matmul256<<<dim3(16, 32), 256, 0, stream>>>(pt1, paz, pt2, 15.f, 1.f); // t1 = 15*az - az@t2
    matmul256<<<dim3(16, 32), 256, 0, stream>>>(pt2, pz, pt1, 13.f, 0.25f);// z' = .25*(13z - z@t1)
    float* tmp = pz; pz = pt2; pt2 = tmp;
  }

  attn3v_kernel<<<dim3(256, 32), 256, 0, stream>>>(ql, k, v, Wm);
  zw_kernel<<<2048, 256, 0, stream>>>(pz, Wm, Um);
  attn1_kernel<<<dim3(16, 32), 256, 0, stream>>>(q, kl, Um, xn /*out_pre*/);
  conv_kernel<<<65536, 256, 0, stream>>>(v, rk, xn);
  gemm_out<<<dim3(512, 8), 256, 0, stream>>>(xn, wout, bout, x, y);
}

// Round 3
// 3587.979 us; speedup vs baseline: 2.3548x; 2.3548x over previous
//
#include <hip/hip_runtime.h>
#include <math.h>

#define NB 4
#define NSEQ 8192
#define DMODEL 512
#define NHEADS 8
#define DHEAD 64
#define NLM 256
#define LTOK 32
#define NBH 32
#define KCONV 33

typedef unsigned short bf16_t;

__device__ __forceinline__ float bf2f(bf16_t u) {
  return __uint_as_float(((unsigned)u) << 16);
}
__device__ __forceinline__ bf16_t f2bf(float f) {
  unsigned u = __float_as_uint(f);
  return (bf16_t)((u + 0x7fffu + ((u >> 16) & 1u)) >> 16);  // RTNE
}
__device__ __forceinline__ void bfpair(unsigned u, float& lo, float& hi) {
  lo = __uint_as_float(u << 16);
  hi = __uint_as_float(u & 0xffff0000u);
}

// ---------------- LayerNorm: one wave per 512-float row, bf16 out ----------------
__global__ __launch_bounds__(256) void ln_kernel(const float* __restrict__ x,
    const float* __restrict__ gamma, const float* __restrict__ beta,
    bf16_t* __restrict__ xn) {
  int row = blockIdx.x * 4 + (threadIdx.x >> 6);
  int lane = threadIdx.x & 63;
  const float4* xr = reinterpret_cast<const float4*>(x + (size_t)row * DMODEL);
  float4 a0 = xr[lane];
  float4 a1 = xr[lane + 64];
  float s  = a0.x + a0.y + a0.z + a0.w + a1.x + a1.y + a1.z + a1.w;
  float s2 = a0.x*a0.x + a0.y*a0.y + a0.z*a0.z + a0.w*a0.w
           + a1.x*a1.x + a1.y*a1.y + a1.z*a1.z + a1.w*a1.w;
  #pragma unroll
  for (int off = 32; off; off >>= 1) {
    s  += __shfl_down(s, off);
    s2 += __shfl_down(s2, off);
  }
  s = __shfl(s, 0); s2 = __shfl(s2, 0);
  float mu = s * (1.0f / DMODEL);
  float var = s2 * (1.0f / DMODEL) - mu * mu;
  float rs = rsqrtf(var + 1e-5f);
  const float4* g4 = reinterpret_cast<const float4*>(gamma);
  const float4* b4 = reinterpret_cast<const float4*>(beta);
  float4 g0 = g4[lane], g1 = g4[lane + 64];
  float4 bb0 = b4[lane], bb1 = b4[lane + 64];
  ushort4 o0, o1;
  o0.x = f2bf((a0.x - mu) * rs * g0.x + bb0.x);
  o0.y = f2bf((a0.y - mu) * rs * g0.y + bb0.y);
  o0.z = f2bf((a0.z - mu) * rs * g0.z + bb0.z);
  o0.w = f2bf((a0.w - mu) * rs * g0.w + bb0.w);
  o1.x = f2bf((a1.x - mu) * rs * g1.x + bb1.x);
  o1.y = f2bf((a1.y - mu) * rs * g1.y + bb1.y);
  o1.z = f2bf((a1.z - mu) * rs * g1.z + bb1.z);
  o1.w = f2bf((a1.w - mu) * rs * g1.w + bb1.w);
  ushort4* o = reinterpret_cast<ushort4*>(xn + (size_t)row * DMODEL);
  o[lane] = o0; o[lane + 64] = o1;
}

// ---------------- QKV GEMM: (32768x512)@(512x1536), bf16 A in, bf16 qkv out ----------------
__global__ __launch_bounds__(256) void gemm_qkv(const bf16_t* __restrict__ A,
    const float* __restrict__ Bm, bf16_t* __restrict__ q, bf16_t* __restrict__ k,
    bf16_t* __restrict__ v) {
  __shared__ float As[16][68];
  __shared__ float Bs[16][68];
  int rowB = blockIdx.x * 64, colB = blockIdx.y * 64;
  int tid = threadIdx.x, tx = tid & 15, ty = tid >> 4;
  float acc[4][4] = {};
  for (int k0 = 0; k0 < DMODEL; k0 += 16) {
    {
      int row = tid >> 2, quad = tid & 3;  // 64 rows x 4 quads of 4 bf16
      const ushort4 a4 = *reinterpret_cast<const ushort4*>(
          A + (size_t)(rowB + row) * DMODEL + k0 + quad * 4);
      As[quad * 4 + 0][row] = bf2f(a4.x);
      As[quad * 4 + 1][row] = bf2f(a4.y);
      As[quad * 4 + 2][row] = bf2f(a4.z);
      As[quad * 4 + 3][row] = bf2f(a4.w);
    }
    #pragma unroll
    for (int i = 0; i < 4; ++i) {
      int idx = tid + i * 256;
      Bs[idx >> 6][idx & 63] = Bm[(size_t)(k0 + (idx >> 6)) * 1536 + colB + (idx & 63)];
    }
    __syncthreads();
    #pragma unroll
    for (int kk = 0; kk < 16; ++kk) {
      float4 a4 = *reinterpret_cast<const float4*>(&As[kk][ty * 4]);
      float4 b4 = *reinterpret_cast<const float4*>(&Bs[kk][tx * 4]);
      acc[0][0] += a4.x*b4.x; acc[0][1] += a4.x*b4.y; acc[0][2] += a4.x*b4.z; acc[0][3] += a4.x*b4.w;
      acc[1][0] += a4.y*b4.x; acc[1][1] += a4.y*b4.y; acc[1][2] += a4.y*b4.z; acc[1][3] += a4.y*b4.w;
      acc[2][0] += a4.z*b4.x; acc[2][1] += a4.z*b4.y; acc[2][2] += a4.z*b4.z; acc[2][3] += a4.z*b4.w;
      acc[3][0] += a4.w*b4.x; acc[3][1] += a4.w*b4.y; acc[3][2] += a4.w*b4.z; acc[3][3] += a4.w*b4.w;
    }
    __syncthreads();
  }
  #pragma unroll
  for (int i = 0; i < 4; ++i) {
    int r = rowB + ty * 4 + i;
    int b = r >> 13, n = r & 8191;
    #pragma unroll
    for (int j = 0; j < 4; ++j) {
      int c = colB + tx * 4 + j;
      int which = c >> 9, hc = c & 511, h = hc >> 6, d = hc & 63;
      float val = acc[i][j];
      bf16_t* dst = (which == 0) ? q : (which == 1 ? k : v);
      if (which == 0) val *= 0.125f;  // dh^-0.5
      dst[((size_t)(b * NHEADS + h) * NSEQ + n) * DHEAD + d] = f2bf(val);
    }
  }
}

// ---------------- landmark mean pooling (q and k), fp32 out ----------------
__global__ void pool_kernel(const bf16_t* __restrict__ q, const bf16_t* __restrict__ k,
                            float* __restrict__ ql, float* __restrict__ kl) {
  int idx = blockIdx.x * 256 + threadIdx.x;  // 2 * 524288
  const int half = NBH * NLM * DHEAD;
  const bf16_t* src = (idx < half) ? q : k;
  float* dst = (idx < half) ? ql : kl;
  int i = (idx < half) ? idx : idx - half;
  int d = i & 63, m = (i >> 6) & 255, bh = i >> 14;
  const bf16_t* p = src + ((size_t)bh * NSEQ + m * LTOK) * DHEAD + d;
  float sum = 0.f;
  #pragma unroll
  for (int t = 0; t < LTOK; ++t) sum += bf2f(p[(size_t)t * DHEAD]);
  dst[i] = sum * (1.0f / LTOK);
}

// ---------------- attn2 = softmax(q_l @ k_l^T), 256x256 per bh ----------------
__global__ __launch_bounds__(256) void attn2_kernel(const float* __restrict__ ql,
    const float* __restrict__ kl, float* __restrict__ a2) {
  __shared__ float qs[64];
  __shared__ float red[256];
  int bh = blockIdx.y, i = blockIdx.x, t = threadIdx.x;
  if (t < 64) qs[t] = ql[((size_t)bh * NLM + i) * DHEAD + t];
  __syncthreads();
  const float* kr = kl + ((size_t)bh * NLM + t) * DHEAD;
  float s = 0.f;
  #pragma unroll
  for (int d = 0; d < 64; ++d) s += qs[d] * kr[d];
  red[t] = s; __syncthreads();
  for (int off = 128; off; off >>= 1) { if (t < off) red[t] = fmaxf(red[t], red[t + off]); __syncthreads(); }
  float mx = red[0]; __syncthreads();
  float p = expf(s - mx);
  red[t] = p; __syncthreads();
  for (int off = 128; off; off >>= 1) { if (t < off) red[t] += red[t + off]; __syncthreads(); }
  a2[((size_t)bh * NLM + i) * NLM + t] = p / red[0];
}

__global__ void zero2_kernel(unsigned int* __restrict__ scal) {
  if (threadIdx.x < 2) scal[threadIdx.x] = 0u;
}

// ---------------- global col/row maxima for pinv init ----------------
__global__ void colrow_kernel(const float* __restrict__ a2, unsigned int* __restrict__ scal) {
  int bh = blockIdx.x & 31, mode = blockIdx.x >> 5;
  int t = threadIdx.x;
  const float* Ab = a2 + (size_t)bh * NLM * NLM;
  float sum = 0.f;
  if (mode == 0) { for (int j = 0; j < NLM; ++j) sum += fabsf(Ab[(size_t)t * NLM + j]); }
  else           { for (int i2 = 0; i2 < NLM; ++i2) sum += fabsf(Ab[(size_t)i2 * NLM + t]); }
  __shared__ float red[256];
  red[t] = sum; __syncthreads();
  for (int off = 128; off; off >>= 1) { if (t < off) red[t] = fmaxf(red[t], red[t + off]); __syncthreads(); }
  if (t == 0) atomicMax(&scal[mode], __float_as_uint(red[0]));  // all values > 0
}

// ---------------- z0 = a^T / (col*row) ----------------
__global__ void zinit_kernel(const float* __restrict__ a2, const unsigned int* __restrict__ scal,
                             float* __restrict__ z) {
  int idx = blockIdx.x * 256 + threadIdx.x;  // 2097152
  float inv = 1.0f / (__uint_as_float(scal[0]) * __uint_as_float(scal[1]));
  int j = idx & 255, i = (idx >> 8) & 255, bh = idx >> 16;
  z[idx] = a2[((size_t)bh * NLM + j) * NLM + i] * inv;
}

// ---------------- batched 256x256 matmul: C = alpha*(s*A - A@B) per bh ----------------
__global__ __launch_bounds__(256) void matmul256(float* __restrict__ C,
    const float* __restrict__ A, const float* __restrict__ Bm, float s, float alpha) {
  __shared__ float As[16][68];
  __shared__ float Bs[16][68];
  int bh = blockIdx.y;
  const float* Ab = A + (size_t)bh * NLM * NLM;
  const float* Bb = Bm + (size_t)bh * NLM * NLM;
  float* Cb = C + (size_t)bh * NLM * NLM;
  int rowB = (blockIdx.x >> 2) * 64, colB = (blockIdx.x & 3) * 64;
  int tid = threadIdx.x, tx = tid & 15, ty = tid >> 4;
  float acc[4][4] = {};
  for (int k0 = 0; k0 < NLM; k0 += 16) {
    #pragma unroll
    for (int i = 0; i < 4; ++i) {
      int idx = tid + i * 256;
      As[idx & 15][idx >> 4] = Ab[(size_t)(rowB + (idx >> 4)) * NLM + k0 + (idx & 15)];
    }
    #pragma unroll
    for (int i = 0; i < 4; ++i) {
      int idx = tid + i * 256;
      Bs[idx >> 6][idx & 63] = Bb[(size_t)(k0 + (idx >> 6)) * NLM + colB + (idx & 63)];
    }
    __syncthreads();
    #pragma unroll
    for (int kk = 0; kk < 16; ++kk) {
      float4 a4 = *reinterpret_cast<const float4*>(&As[kk][ty * 4]);
      float4 b4 = *reinterpret_cast<const float4*>(&Bs[kk][tx * 4]);
      acc[0][0] += a4.x*b4.x; acc[0][1] += a4.x*b4.y; acc[0][2] += a4.x*b4.z; acc[0][3] += a4.x*b4.w;
      acc[1][0] += a4.y*b4.x; acc[1][1] += a4.y*b4.y; acc[1][2] += a4.y*b4.z; acc[1][3] += a4.y*b4.w;
      acc[2][0] += a4.z*b4.x; acc[2][1] += a4.z*b4.y; acc[2][2] += a4.z*b4.z; acc[2][3] += a4.z*b4.w;
      acc[3][0] += a4.w*b4.x; acc[3][1] += a4.w*b4.y; acc[3][2] += a4.w*b4.z; acc[3][3] += a4.w*b4.w;
    }
    __syncthreads();
  }
  #pragma unroll
  for (int i = 0; i < 4; ++i) {
    int r = rowB + ty * 4 + i;
    #pragma unroll
    for (int j = 0; j < 4; ++j) {
      int c = colB + tx * 4 + j;
      float aij = (s != 0.0f) ? Ab[(size_t)r * NLM + c] : 0.0f;
      Cb[(size_t)r * NLM + c] = alpha * (s * aij - acc[i][j]);
    }
  }
}

// ---------------- flash attn3@v: W_part = softmax-partial(q_l @ k^T) @ v ----------------
// grid (chunk=2, lmtile=4, bh=32); 64-lm x 64-d acc per block over 4096 n rows
__global__ __launch_bounds__(256) void attn3v_flash(const float* __restrict__ ql,
    const bf16_t* __restrict__ k, const bf16_t* __restrict__ v,
    float* __restrict__ Wpart, float* __restrict__ mlpart) {
  __shared__ float Qt[64][68];  // [d][lm]
  __shared__ float Kt[64][68];  // [d][n]
  __shared__ float Vs[64][68];  // [n][d]
  __shared__ float Pt[64][68];  // [n][lm]
  int chunk = blockIdx.x, lmt = blockIdx.y, bh = blockIdx.z;
  int tid = threadIdx.x, tx = tid & 15, ty = tid >> 4;
  int lm0 = lmt * 64;
  {
    int lm = tid >> 2, part = tid & 3;
    const float4* qr = reinterpret_cast<const float4*>(
        ql + ((size_t)bh * NLM + lm0 + lm) * DHEAD + part * 16);
    float4 q0 = qr[0], q1 = qr[1], q2 = qr[2], q3 = qr[3];
    int d0 = part * 16;
    Qt[d0+ 0][lm] = q0.x; Qt[d0+ 1][lm] = q0.y; Qt[d0+ 2][lm] = q0.z; Qt[d0+ 3][lm] = q0.w;
    Qt[d0+ 4][lm] = q1.x; Qt[d0+ 5][lm] = q1.y; Qt[d0+ 6][lm] = q1.z; Qt[d0+ 7][lm] = q1.w;
    Qt[d0+ 8][lm] = q2.x; Qt[d0+ 9][lm] = q2.y; Qt[d0+10][lm] = q2.z; Qt[d0+11][lm] = q2.w;
    Qt[d0+12][lm] = q3.x; Qt[d0+13][lm] = q3.y; Qt[d0+14][lm] = q3.z; Qt[d0+15][lm] = q3.w;
  }
  float acc[4][4] = {};
  float mreg[4] = {-1e30f, -1e30f, -1e30f, -1e30f};
  float lreg[4] = {0.f, 0.f, 0.f, 0.f};
  const bf16_t* kb = k + (size_t)bh * NSEQ * DHEAD;
  const bf16_t* vb = v + (size_t)bh * NSEQ * DHEAD;
  __syncthreads();
  for (int it = 0; it < 64; ++it) {
    int n0 = chunk * 4096 + it * 64;
    {  // stage K,V subtile (64 rows x 64 d, bf16 -> fp32 LDS)
      int jj = tid >> 2, part = tid & 3;
      const uint4* kr = reinterpret_cast<const uint4*>(kb + (size_t)(n0 + jj) * DHEAD);
      uint4 ka = kr[part * 2], ka2 = kr[part * 2 + 1];
      const uint4* vr = reinterpret_cast<const uint4*>(vb + (size_t)(n0 + jj) * DHEAD);
      uint4 va = vr[part * 2], va2 = vr[part * 2 + 1];
      int d0 = part * 16;
      float f0, f1;
      bfpair(ka.x, f0, f1);  Kt[d0+ 0][jj] = f0; Kt[d0+ 1][jj] = f1;
      bfpair(ka.y, f0, f1);  Kt[d0+ 2][jj] = f0; Kt[d0+ 3][jj] = f1;
      bfpair(ka.z, f0, f1);  Kt[d0+ 4][jj] = f0; Kt[d0+ 5][jj] = f1;
      bfpair(ka.w, f0, f1);  Kt[d0+ 6][jj] = f0; Kt[d0+ 7][jj] = f1;
      bfpair(ka2.x, f0, f1); Kt[d0+ 8][jj] = f0; Kt[d0+ 9][jj] = f1;
      bfpair(ka2.y, f0, f1); Kt[d0+10][jj] = f0; Kt[d0+11][jj] = f1;
      bfpair(ka2.z, f0, f1); Kt[d0+12][jj] = f0; Kt[d0+13][jj] = f1;
      bfpair(ka2.w, f0, f1); Kt[d0+14][jj] = f0; Kt[d0+15][jj] = f1;
      bfpair(va.x, f0, f1);  Vs[jj][d0+ 0] = f0; Vs[jj][d0+ 1] = f1;
      bfpair(va.y, f0, f1);  Vs[jj][d0+ 2] = f0; Vs[jj][d0+ 3] = f1;
      bfpair(va.z, f0, f1);  Vs[jj][d0+ 4] = f0; Vs[jj][d0+ 5] = f1;
      bfpair(va.w, f0, f1);  Vs[jj][d0+ 6] = f0; Vs[jj][d0+ 7] = f1;
      bfpair(va2.x, f0, f1); Vs[jj][d0+ 8] = f0; Vs[jj][d0+ 9] = f1;
      bfpair(va2.y, f0, f1); Vs[jj][d0+10] = f0; Vs[jj][d0+11] = f1;
      bfpair(va2.z, f0, f1); Vs[jj][d0+12] = f0; Vs[jj][d0+13] = f1;
      bfpair(va2.w, f0, f1); Vs[jj][d0+14] = f0; Vs[jj][d0+15] = f1;
    }
    __syncthreads();
    // ---- S tile: 4 lm x 4 n per thread ----
    float s[4][4] = {};
    #pragma unroll 16
    for (int dk = 0; dk < 64; ++dk) {
      float4 a4 = *reinterpret_cast<const float4*>(&Qt[dk][ty * 4]);
      float4 b4 = *reinterpret_cast<const float4*>(&Kt[dk][tx * 4]);
      s[0][0] += a4.x*b4.x; s[0][1] += a4.x*b4.y; s[0][2] += a4.x*b4.z; s[0][3] += a4.x*b4.w;
      s[1][0] += a4.y*b4.x; s[1][1] += a4.y*b4.y; s[1][2] += a4.y*b4.z; s[1][3] += a4.y*b4.w;
      s[2][0] += a4.z*b4.x; s[2][1] += a4.z*b4.y; s[2][2] += a4.z*b4.z; s[2][3] += a4.z*b4.w;
      s[3][0] += a4.w*b4.x; s[3][1] += a4.w*b4.y; s[3][2] += a4.w*b4.z; s[3][3] += a4.w*b4.w;
    }
    // ---- online softmax (stats per lm, consistent across the 16 tx lanes) ----
    #pragma unroll
    for (int i = 0; i < 4; ++i) {
      float mt = fmaxf(fmaxf(s[i][0], s[i][1]), fmaxf(s[i][2], s[i][3]));
      #pragma unroll
      for (int off = 1; off < 16; off <<= 1) mt = fmaxf(mt, __shfl_xor(mt, off));
      float mnew = fmaxf(mreg[i], mt);
      float corr = __expf(mreg[i] - mnew);
      float ts = 0.f;
      #pragma unroll
      for (int j = 0; j < 4; ++j) { s[i][j] = __expf(s[i][j] - mnew); ts += s[i][j]; }
      #pragma unroll
      for (int off = 1; off < 16; off <<= 1) ts += __shfl_xor(ts, off);
      lreg[i] = lreg[i] * corr + ts;
      mreg[i] = mnew;
      acc[i][0] *= corr; acc[i][1] *= corr; acc[i][2] *= corr; acc[i][3] *= corr;
    }
    // hand P to (lm,d)-layout threads via LDS transpose
    #pragma unroll
    for (int i = 0; i < 4; ++i)
      #pragma unroll
      for (int j = 0; j < 4; ++j) Pt[tx * 4 + j][ty * 4 + i] = s[i][j];
    __syncthreads();
    // ---- PV: acc[lm][d] += sum_j P[lm][j] * V[j][d] ----
    #pragma unroll 16
    for (int j = 0; j < 64; ++j) {
      float4 p4 = *reinterpret_cast<const float4*>(&Pt[j][ty * 4]);
      float4 v4 = *reinterpret_cast<const float4*>(&Vs[j][tx * 4]);
      acc[0][0] += p4.x*v4.x; acc[0][1] += p4.x*v4.y; acc[0][2] += p4.x*v4.z; acc[0][3] += p4.x*v4.w;
      acc[1][0] += p4.y*v4.x; acc[1][1] += p4.y*v4.y; acc[1][2] += p4.y*v4.z; acc[1][3] += p4.y*v4.w;
      acc[2][0] += p4.z*v4.x; acc[2][1] += p4.z*v4.y; acc[2][2] += p4.z*v4.z; acc[2][3] += p4.z*v4.w;
      acc[3][0] += p4.w*v4.x; acc[3][1] += p4.w*v4.y; acc[3][2] += p4.w*v4.z; acc[3][3] += p4.w*v4.w;
    }
    __syncthreads();
  }
  size_t obase = ((size_t)(chunk * NBH + bh) * NLM + lm0 + ty * 4);
  #pragma unroll
  for (int i = 0; i < 4; ++i) {
    float4 w4 = make_float4(acc[i][0], acc[i][1], acc[i][2], acc[i][3]);
    *reinterpret_cast<float4*>(&Wpart[(obase + i) * DHEAD + tx * 4]) = w4;
  }
  if (tx == 0) {
    #pragma unroll
    for (int i = 0; i < 4; ++i) {
      mlpart[(obase + i) * 2]     = mreg[i];
      mlpart[(obase + i) * 2 + 1] = lreg[i];
    }
  }
}

// combine the 2 n-chunks: W = (W0*e0 + W1*e1) / (l0*e0 + l1*e1)
__global__ void attn3v_combine(const float* __restrict__ Wpart,
    const float* __restrict__ mlpart, float* __restrict__ Wm) {
  int idx = blockIdx.x * 256 + threadIdx.x;  // 524288
  int d = idx & 63;
  int s0 = idx >> 6;                          // bh*256 + lm
  const int CH = NBH * NLM;                   // 8192
  float m0 = mlpart[s0 * 2], l0 = mlpart[s0 * 2 + 1];
  float m1 = mlpart[(CH + s0) * 2], l1 = mlpart[(CH + s0) * 2 + 1];
  float M = fmaxf(m0, m1);
  float e0 = __expf(m0 - M), e1 = __expf(m1 - M);
  float w = Wpart[(size_t)s0 * DHEAD + d] * e0 + Wpart[((size_t)CH + s0) * DHEAD + d] * e1;
  Wm[idx] = w / (l0 * e0 + l1 * e1);
}

// ---------------- U = Z @ W : (256x256)@(256x64) per bh ----------------
__global__ void zw_kernel(const float* __restrict__ z, const float* __restrict__ W,
                          float* __restrict__ U) {
  int idx = blockIdx.x * 256 + threadIdx.x;  // NBH*NLM*DHEAD
  int d = idx & 63, i = (idx >> 6) & 255, bh = idx >> 14;
  const float* zr = z + ((size_t)bh * NLM + i) * NLM;
  const float* Wb = W + (size_t)bh * NLM * DHEAD + d;
  float acc = 0.f;
  for (int j = 0; j < NLM; ++j) acc += zr[j] * Wb[(size_t)j * DHEAD];
  U[idx] = acc;
}

// ---------------- out = softmax(q @ k_l^T) @ U, k_l & U staged in LDS ----------------
__global__ __launch_bounds__(256, 1) void attn1_kernel(const bf16_t* __restrict__ q,
    const float* __restrict__ kl, const float* __restrict__ U, bf16_t* __restrict__ outp) {
  __shared__ float kls[NLM][65];
  __shared__ float Us[NLM][64];
  __shared__ float qs[4][64];
  __shared__ float ps[4][256];
  int bh = blockIdx.y, t = threadIdx.x;
  int w = t >> 6, lane = t & 63;
  const float* klb = kl + (size_t)bh * NLM * DHEAD;
  const float* Ub  = U  + (size_t)bh * NLM * DHEAD;
  for (int p = t; p < NLM * DHEAD; p += 256) {
    int r = p >> 6, c = p & 63;
    kls[r][c] = klb[p];
    Us[r][c]  = Ub[p];
  }
  __syncthreads();
  int b = bh >> 3, h = bh & 7;
  int q0 = blockIdx.x * 512;
  const bf16_t* qb = q + (size_t)bh * NSEQ * DHEAD;
  for (int qq = q0 + w; qq < q0 + 512; qq += 4) {
    qs[w][lane] = bf2f(qb[(size_t)qq * DHEAD + lane]);
    __syncthreads();
    float sc[4]; float mx = -1e30f;
    #pragma unroll
    for (int rr = 0; rr < 4; ++rr) {
      int j = lane + rr * 64;
      float s = 0.f;
      #pragma unroll
      for (int d = 0; d < 64; ++d) s += qs[w][d] * kls[j][d];
      sc[rr] = s; mx = fmaxf(mx, s);
    }
    #pragma unroll
    for (int off = 32; off; off >>= 1) mx = fmaxf(mx, __shfl_xor(mx, off));
    float lsum = 0.f;
    #pragma unroll
    for (int rr = 0; rr < 4; ++rr) { sc[rr] = expf(sc[rr] - mx); lsum += sc[rr]; }
    #pragma unroll
    for (int off = 32; off; off >>= 1) lsum += __shfl_xor(lsum, off);
    float inv = 1.0f / lsum;
    #pragma unroll
    for (int rr = 0; rr < 4; ++rr) ps[w][lane + rr * 64] = sc[rr] * inv;
    __syncthreads();
    float acc = 0.f;
    for (int j = 0; j < NLM; ++j) acc += ps[w][j] * Us[j][lane];
    outp[((size_t)(b * NSEQ + qq)) * DMODEL + h * DHEAD + lane] = f2bf(acc);
    __syncthreads();
  }
}

// ---------------- depthwise conv residual, added into bf16 out_pre ----------------
__global__ void conv_kernel(const bf16_t* __restrict__ v, const float* __restrict__ rk,
                            bf16_t* __restrict__ outp) {
  int idx = blockIdx.x * 256 + threadIdx.x;  // NB*NSEQ*DMODEL
  int d = idx & 63, h = (idx >> 6) & 7, n = (idx >> 9) & 8191, b = idx >> 22;
  const bf16_t* vb = v + ((size_t)(b * NHEADS + h) * NSEQ) * DHEAD + d;
  const float* wk = rk + h * KCONV;
  float acc = 0.f;
  #pragma unroll
  for (int tp = 0; tp < KCONV; ++tp) {
    int nn = n + tp - 16;
    if (nn >= 0 && nn < NSEQ) acc += bf2f(vb[(size_t)nn * DHEAD]) * wk[tp];
  }
  outp[idx] = f2bf(bf2f(outp[idx]) + acc);
}

// ---------------- final: y = x + out_pre @ w_out + b_out ----------------
__global__ __launch_bounds__(256) void gemm_out(const bf16_t* __restrict__ A,
    const float* __restrict__ Bm, const float* __restrict__ bo,
    const float* __restrict__ x, float* __restrict__ y) {
  __shared__ float As[16][68];
  __shared__ float Bs[16][68];
  int rowB = blockIdx.x * 64, colB = blockIdx.y * 64;
  int tid = threadIdx.x, tx = tid & 15, ty = tid >> 4;
  float acc[4][4] = {};
  for (int k0 = 0; k0 < DMODEL; k0 += 16) {
    {
      int row = tid >> 2, quad = tid & 3;
      const ushort4 a4 = *reinterpret_cast<const ushort4*>(
          A + (size_t)(rowB + row) * DMODEL + k0 + quad * 4);
      As[quad * 4 + 0][row] = bf2f(a4.x);
      As[quad * 4 + 1][row] = bf2f(a4.y);
      As[quad * 4 + 2][row] = bf2f(a4.z);
      As[quad * 4 + 3][row] = bf2f(a4.w);
    }
    #pragma unroll
    for (int i = 0; i < 4; ++i) {
      int idx = tid + i * 256;
      Bs[idx >> 6][idx & 63] = Bm[(size_t)(k0 + (idx >> 6)) * DMODEL + colB + (idx & 63)];
    }
    __syncthreads();
    #pragma unroll
    for (int kk = 0; kk < 16; ++kk) {
      float4 a4 = *reinterpret_cast<const float4*>(&As[kk][ty * 4]);
      float4 b4 = *reinterpret_cast<const float4*>(&Bs[kk][tx * 4]);
      acc[0][0] += a4.x*b4.x; acc[0][1] += a4.x*b4.y; acc[0][2] += a4.x*b4.z; acc[0][3] += a4.x*b4.w;
      acc[1][0] += a4.y*b4.x; acc[1][1] += a4.y*b4.y; acc[1][2] += a4.y*b4.z; acc[1][3] += a4.y*b4.w;
      acc[2][0] += a4.z*b4.x; acc[2][1] += a4.z*b4.y; acc[2][2] += a4.z*b4.z; acc[2][3] += a4.z*b4.w;
      acc[3][0] += a4.w*b4.x; acc[3][1] += a4.w*b4.y; acc[3][2] += a4.w*b4.z; acc[3][3] += a4.w*b4.w;
    }
    __syncthreads();
  }
  #pragma unroll
  for (int i = 0; i < 4; ++i) {
    int r = rowB + ty * 4 + i;
    #pragma unroll
    for (int j = 0; j < 4; ++j) {
      int c = colB + tx * 4 + j;
      y[(size_t)r * DMODEL + c] = x[(size_t)r * DMODEL + c] + bo[c] + acc[i][j];
    }
  }
}

extern "C" void kernel_launch(void* const* d_in, const int* in_sizes, int n_in,
                              void* d_out, int out_size, void* d_ws, size_t ws_size,
                              hipStream_t stream) {
  const float* x     = (const float*)d_in[0];
  const float* gamma = (const float*)d_in[1];
  const float* beta  = (const float*)d_in[2];
  const float* wqkv  = (const float*)d_in[3];
  const float* wout  = (const float*)d_in[4];
  const float* bout  = (const float*)d_in[5];
  const float* rk    = (const float*)d_in[6];
  float* y = (float*)d_out;

  // ---- workspace layout: 176 MB + 8 B total ----
  char* wsb = (char*)d_ws;
  bf16_t* xn = (bf16_t*)(wsb);                   // 32 MB, reused as out_pre
  bf16_t* q  = (bf16_t*)(wsb + 33554432ull);     // 32 MB
  bf16_t* k  = (bf16_t*)(wsb + 67108864ull);     // 32 MB
  bf16_t* v  = (bf16_t*)(wsb + 100663296ull);    // 32 MB
  float* a2  = (float*)(wsb + 134217728ull);     // 8 MB
  float* z   = (float*)(wsb + 142606336ull);     // 8 MB
  float* az  = (float*)(wsb + 150994944ull);     // 8 MB (dead after pinv -> Wpart)
  float* t1  = (float*)(wsb + 159383552ull);     // 8 MB (dead after pinv -> mlpart)
  float* t2  = (float*)(wsb + 167772160ull);     // 8 MB
  float* ql  = (float*)(wsb + 176160768ull);     // 2 MB
  float* kl  = (float*)(wsb + 178257920ull);     // 2 MB
  float* Wm  = (float*)(wsb + 180355072ull);     // 2 MB
  float* Um  = (float*)(wsb + 182452224ull);     // 2 MB
  unsigned int* scal = (unsigned int*)(wsb + 184549376ull);  // 8 B

  ln_kernel<<<8192, 256, 0, stream>>>(x, gamma, beta, xn);
  gemm_qkv<<<dim3(512, 24), 256, 0, stream>>>(xn, wqkv, q, k, v);
  pool_kernel<<<4096, 256, 0, stream>>>(q, k, ql, kl);
  attn2_kernel<<<dim3(256, 32), 256, 0, stream>>>(ql, kl, a2);
  zero2_kernel<<<1, 64, 0, stream>>>(scal);
  colrow_kernel<<<64, 256, 0, stream>>>(a2, scal);
  zinit_kernel<<<8192, 256, 0, stream>>>(a2, scal, z);

  float *pz = z, *paz = az, *pt1 = t1, *pt2 = t2;
  for (int it = 0; it < 6; ++it) {
    matmul256<<<dim3(16, 32), 256, 0, stream>>>(paz, a2, pz, 0.f, -1.f);   // az = a@z
    matmul256<<<dim3(16, 32), 256, 0, stream>>>(pt2, paz, paz, 7.f, 1.f);  // t2 = 7*az - az@az
    matmul256<<<dim3(16, 32), 256, 0, stream>>>(pt1, paz, pt2, 15.f, 1.f); // t1 = 15*az - az@t2
    matmul256<<<dim3(16, 32), 256, 0, stream>>>(pt2, pz, pt1, 13.f, 0.25f);// z' = .25*(13z - z@t1)
    float* tmp = pz; pz = pt2; pt2 = tmp;
  }
  // after 6 swaps pz == z; az/t1/t2/a2 are dead -> reuse for flash partials
  float* Wpart  = az;   // 2*32*256*64 fp32 = 4 MB
  float* mlpart = t1;   // 2*32*256*2 fp32 = 128 KB

  attn3v_flash<<<dim3(2, 4, 32), 256, 0, stream>>>(ql, k, v, Wpart, mlpart);
  attn3v_combine<<<2048, 256, 0, stream>>>(Wpart, mlpart, Wm);
  zw_kernel<<<2048, 256, 0, stream>>>(pz, Wm, Um);
  attn1_kernel<<<dim3(16, 32), 256, 0, stream>>>(q, kl, Um, xn /*out_pre*/);
  conv_kernel<<<65536, 256, 0, stream>>>(v, rk, xn);
  gemm_out<<<dim3(512, 8), 256, 0, stream>>>(xn, wout, bout, x, y);
}

// Round 4
// 2464.346 us; speedup vs baseline: 3.4285x; 1.4560x over previous
//
#include <hip/hip_runtime.h>
#include <math.h>

#define NB 4
#define NSEQ 8192
#define DMODEL 512
#define NHEADS 8
#define DHEAD 64
#define NLM 256
#define LTOK 32
#define NBH 32
#define KCONV 33

typedef unsigned short bf16_t;

__device__ __forceinline__ float bf2f(bf16_t u) {
  return __uint_as_float(((unsigned)u) << 16);
}
__device__ __forceinline__ bf16_t f2bf(float f) {
  unsigned u = __float_as_uint(f);
  return (bf16_t)((u + 0x7fffu + ((u >> 16) & 1u)) >> 16);  // RTNE
}
__device__ __forceinline__ void bfpair(unsigned u, float& lo, float& hi) {
  lo = __uint_as_float(u << 16);
  hi = __uint_as_float(u & 0xffff0000u);
}

// ---------------- LayerNorm: one wave per 512-float row, bf16 out ----------------
__global__ __launch_bounds__(256) void ln_kernel(const float* __restrict__ x,
    const float* __restrict__ gamma, const float* __restrict__ beta,
    bf16_t* __restrict__ xn) {
  int row = blockIdx.x * 4 + (threadIdx.x >> 6);
  int lane = threadIdx.x & 63;
  const float4* xr = reinterpret_cast<const float4*>(x + (size_t)row * DMODEL);
  float4 a0 = xr[lane];
  float4 a1 = xr[lane + 64];
  float s  = a0.x + a0.y + a0.z + a0.w + a1.x + a1.y + a1.z + a1.w;
  float s2 = a0.x*a0.x + a0.y*a0.y + a0.z*a0.z + a0.w*a0.w
           + a1.x*a1.x + a1.y*a1.y + a1.z*a1.z + a1.w*a1.w;
  #pragma unroll
  for (int off = 32; off; off >>= 1) {
    s  += __shfl_down(s, off);
    s2 += __shfl_down(s2, off);
  }
  s = __shfl(s, 0); s2 = __shfl(s2, 0);
  float mu = s * (1.0f / DMODEL);
  float var = s2 * (1.0f / DMODEL) - mu * mu;
  float rs = rsqrtf(var + 1e-5f);
  const float4* g4 = reinterpret_cast<const float4*>(gamma);
  const float4* b4 = reinterpret_cast<const float4*>(beta);
  float4 g0 = g4[lane], g1 = g4[lane + 64];
  float4 bb0 = b4[lane], bb1 = b4[lane + 64];
  ushort4 o0, o1;
  o0.x = f2bf((a0.x - mu) * rs * g0.x + bb0.x);
  o0.y = f2bf((a0.y - mu) * rs * g0.y + bb0.y);
  o0.z = f2bf((a0.z - mu) * rs * g0.z + bb0.z);
  o0.w = f2bf((a0.w - mu) * rs * g0.w + bb0.w);
  o1.x = f2bf((a1.x - mu) * rs * g1.x + bb1.x);
  o1.y = f2bf((a1.y - mu) * rs * g1.y + bb1.y);
  o1.z = f2bf((a1.z - mu) * rs * g1.z + bb1.z);
  o1.w = f2bf((a1.w - mu) * rs * g1.w + bb1.w);
  ushort4* o = reinterpret_cast<ushort4*>(xn + (size_t)row * DMODEL);
  o[lane] = o0; o[lane + 64] = o1;
}

// ---------------- QKV GEMM: (32768x512)@(512x1536), bf16 A in, bf16 qkv out ----------------
__global__ __launch_bounds__(256) void gemm_qkv(const bf16_t* __restrict__ A,
    const float* __restrict__ Bm, bf16_t* __restrict__ q, bf16_t* __restrict__ k,
    bf16_t* __restrict__ v) {
  __shared__ float As[16][68];
  __shared__ float Bs[16][68];
  int rowB = blockIdx.x * 64, colB = blockIdx.y * 64;
  int tid = threadIdx.x, tx = tid & 15, ty = tid >> 4;
  float acc[4][4] = {};
  for (int k0 = 0; k0 < DMODEL; k0 += 16) {
    {
      int row = tid >> 2, quad = tid & 3;  // 64 rows x 4 quads of 4 bf16
      const ushort4 a4 = *reinterpret_cast<const ushort4*>(
          A + (size_t)(rowB + row) * DMODEL + k0 + quad * 4);
      As[quad * 4 + 0][row] = bf2f(a4.x);
      As[quad * 4 + 1][row] = bf2f(a4.y);
      As[quad * 4 + 2][row] = bf2f(a4.z);
      As[quad * 4 + 3][row] = bf2f(a4.w);
    }
    #pragma unroll
    for (int i = 0; i < 4; ++i) {
      int idx = tid + i * 256;
      Bs[idx >> 6][idx & 63] = Bm[(size_t)(k0 + (idx >> 6)) * 1536 + colB + (idx & 63)];
    }
    __syncthreads();
    #pragma unroll
    for (int kk = 0; kk < 16; ++kk) {
      float4 a4 = *reinterpret_cast<const float4*>(&As[kk][ty * 4]);
      float4 b4 = *reinterpret_cast<const float4*>(&Bs[kk][tx * 4]);
      acc[0][0] += a4.x*b4.x; acc[0][1] += a4.x*b4.y; acc[0][2] += a4.x*b4.z; acc[0][3] += a4.x*b4.w;
      acc[1][0] += a4.y*b4.x; acc[1][1] += a4.y*b4.y; acc[1][2] += a4.y*b4.z; acc[1][3] += a4.y*b4.w;
      acc[2][0] += a4.z*b4.x; acc[2][1] += a4.z*b4.y; acc[2][2] += a4.z*b4.z; acc[2][3] += a4.z*b4.w;
      acc[3][0] += a4.w*b4.x; acc[3][1] += a4.w*b4.y; acc[3][2] += a4.w*b4.z; acc[3][3] += a4.w*b4.w;
    }
    __syncthreads();
  }
  #pragma unroll
  for (int i = 0; i < 4; ++i) {
    int r = rowB + ty * 4 + i;
    int b = r >> 13, n = r & 8191;
    #pragma unroll
    for (int j = 0; j < 4; ++j) {
      int c = colB + tx * 4 + j;
      int which = c >> 9, hc = c & 511, h = hc >> 6, d = hc & 63;
      float val = acc[i][j];
      bf16_t* dst = (which == 0) ? q : (which == 1 ? k : v);
      if (which == 0) val *= 0.125f;  // dh^-0.5
      dst[((size_t)(b * NHEADS + h) * NSEQ + n) * DHEAD + d] = f2bf(val);
    }
  }
}

// ---------------- landmark mean pooling (q and k), fp32 out ----------------
__global__ void pool_kernel(const bf16_t* __restrict__ q, const bf16_t* __restrict__ k,
                            float* __restrict__ ql, float* __restrict__ kl) {
  int idx = blockIdx.x * 256 + threadIdx.x;  // 2 * 524288
  const int half = NBH * NLM * DHEAD;
  const bf16_t* src = (idx < half) ? q : k;
  float* dst = (idx < half) ? ql : kl;
  int i = (idx < half) ? idx : idx - half;
  int d = i & 63, m = (i >> 6) & 255, bh = i >> 14;
  const bf16_t* p = src + ((size_t)bh * NSEQ + m * LTOK) * DHEAD + d;
  float sum = 0.f;
  #pragma unroll
  for (int t = 0; t < LTOK; ++t) sum += bf2f(p[(size_t)t * DHEAD]);
  dst[i] = sum * (1.0f / LTOK);
}

// ---------------- attn2 = softmax(q_l @ k_l^T), 256x256 per bh ----------------
__global__ __launch_bounds__(256) void attn2_kernel(const float* __restrict__ ql,
    const float* __restrict__ kl, float* __restrict__ a2) {
  __shared__ float qs[64];
  __shared__ float red[256];
  int bh = blockIdx.y, i = blockIdx.x, t = threadIdx.x;
  if (t < 64) qs[t] = ql[((size_t)bh * NLM + i) * DHEAD + t];
  __syncthreads();
  const float* kr = kl + ((size_t)bh * NLM + t) * DHEAD;
  float s = 0.f;
  #pragma unroll
  for (int d = 0; d < 64; ++d) s += qs[d] * kr[d];
  red[t] = s; __syncthreads();
  for (int off = 128; off; off >>= 1) { if (t < off) red[t] = fmaxf(red[t], red[t + off]); __syncthreads(); }
  float mx = red[0]; __syncthreads();
  float p = expf(s - mx);
  red[t] = p; __syncthreads();
  for (int off = 128; off; off >>= 1) { if (t < off) red[t] += red[t + off]; __syncthreads(); }
  a2[((size_t)bh * NLM + i) * NLM + t] = p / red[0];
}

__global__ void zero2_kernel(unsigned int* __restrict__ scal) {
  if (threadIdx.x < 2) scal[threadIdx.x] = 0u;
}

// ---------------- global col/row maxima for pinv init ----------------
__global__ void colrow_kernel(const float* __restrict__ a2, unsigned int* __restrict__ scal) {
  int bh = blockIdx.x & 31, mode = blockIdx.x >> 5;
  int t = threadIdx.x;
  const float* Ab = a2 + (size_t)bh * NLM * NLM;
  float sum = 0.f;
  if (mode == 0) { for (int j = 0; j < NLM; ++j) sum += fabsf(Ab[(size_t)t * NLM + j]); }
  else           { for (int i2 = 0; i2 < NLM; ++i2) sum += fabsf(Ab[(size_t)i2 * NLM + t]); }
  __shared__ float red[256];
  red[t] = sum; __syncthreads();
  for (int off = 128; off; off >>= 1) { if (t < off) red[t] = fmaxf(red[t], red[t + off]); __syncthreads(); }
  if (t == 0) atomicMax(&scal[mode], __float_as_uint(red[0]));  // all values > 0
}

// ---------------- z0 = a^T / (col*row) ----------------
__global__ void zinit_kernel(const float* __restrict__ a2, const unsigned int* __restrict__ scal,
                             float* __restrict__ z) {
  int idx = blockIdx.x * 256 + threadIdx.x;  // 2097152
  float inv = 1.0f / (__uint_as_float(scal[0]) * __uint_as_float(scal[1]));
  int j = idx & 255, i = (idx >> 8) & 255, bh = idx >> 16;
  z[idx] = a2[((size_t)bh * NLM + j) * NLM + i] * inv;
}

// ---------------- batched 256x256 matmul: C = alpha*(s*A - A@B) per bh ----------------
__global__ __launch_bounds__(256) void matmul256(float* __restrict__ C,
    const float* __restrict__ A, const float* __restrict__ Bm, float s, float alpha) {
  __shared__ float As[16][68];
  __shared__ float Bs[16][68];
  int bh = blockIdx.y;
  const float* Ab = A + (size_t)bh * NLM * NLM;
  const float* Bb = Bm + (size_t)bh * NLM * NLM;
  float* Cb = C + (size_t)bh * NLM * NLM;
  int rowB = (blockIdx.x >> 2) * 64, colB = (blockIdx.x & 3) * 64;
  int tid = threadIdx.x, tx = tid & 15, ty = tid >> 4;
  float acc[4][4] = {};
  for (int k0 = 0; k0 < NLM; k0 += 16) {
    #pragma unroll
    for (int i = 0; i < 4; ++i) {
      int idx = tid + i * 256;
      As[idx & 15][idx >> 4] = Ab[(size_t)(rowB + (idx >> 4)) * NLM + k0 + (idx & 15)];
    }
    #pragma unroll
    for (int i = 0; i < 4; ++i) {
      int idx = tid + i * 256;
      Bs[idx >> 6][idx & 63] = Bb[(size_t)(k0 + (idx >> 6)) * NLM + colB + (idx & 63)];
    }
    __syncthreads();
    #pragma unroll
    for (int kk = 0; kk < 16; ++kk) {
      float4 a4 = *reinterpret_cast<const float4*>(&As[kk][ty * 4]);
      float4 b4 = *reinterpret_cast<const float4*>(&Bs[kk][tx * 4]);
      acc[0][0] += a4.x*b4.x; acc[0][1] += a4.x*b4.y; acc[0][2] += a4.x*b4.z; acc[0][3] += a4.x*b4.w;
      acc[1][0] += a4.y*b4.x; acc[1][1] += a4.y*b4.y; acc[1][2] += a4.y*b4.z; acc[1][3] += a4.y*b4.w;
      acc[2][0] += a4.z*b4.x; acc[2][1] += a4.z*b4.y; acc[2][2] += a4.z*b4.z; acc[2][3] += a4.z*b4.w;
      acc[3][0] += a4.w*b4.x; acc[3][1] += a4.w*b4.y; acc[3][2] += a4.w*b4.z; acc[3][3] += a4.w*b4.w;
    }
    __syncthreads();
  }
  #pragma unroll
  for (int i = 0; i < 4; ++i) {
    int r = rowB + ty * 4 + i;
    #pragma unroll
    for (int j = 0; j < 4; ++j) {
      int c = colB + tx * 4 + j;
      float aij = (s != 0.0f) ? Ab[(size_t)r * NLM + c] : 0.0f;
      Cb[(size_t)r * NLM + c] = alpha * (s * aij - acc[i][j]);
    }
  }
}

// ---------------- flash attn3@v: W_part = softmax-partial(q_l @ k^T) @ v ----------------
// grid (chunk=2, lmtile=4, bh=32); 64-lm x 64-d acc per block over 4096 n rows
__global__ __launch_bounds__(256) void attn3v_flash(const float* __restrict__ ql,
    const bf16_t* __restrict__ k, const bf16_t* __restrict__ v,
    float* __restrict__ Wpart, float* __restrict__ mlpart) {
  __shared__ float Qt[64][68];  // [d][lm]
  __shared__ float Kt[64][68];  // [d][n]
  __shared__ float Vs[64][68];  // [n][d]
  __shared__ float Pt[64][68];  // [n][lm]
  int chunk = blockIdx.x, lmt = blockIdx.y, bh = blockIdx.z;
  int tid = threadIdx.x, tx = tid & 15, ty = tid >> 4;
  int lm0 = lmt * 64;
  {
    int lm = tid >> 2, part = tid & 3;
    const float4* qr = reinterpret_cast<const float4*>(
        ql + ((size_t)bh * NLM + lm0 + lm) * DHEAD + part * 16);
    float4 q0 = qr[0], q1 = qr[1], q2 = qr[2], q3 = qr[3];
    int d0 = part * 16;
    Qt[d0+ 0][lm] = q0.x; Qt[d0+ 1][lm] = q0.y; Qt[d0+ 2][lm] = q0.z; Qt[d0+ 3][lm] = q0.w;
    Qt[d0+ 4][lm] = q1.x; Qt[d0+ 5][lm] = q1.y; Qt[d0+ 6][lm] = q1.z; Qt[d0+ 7][lm] = q1.w;
    Qt[d0+ 8][lm] = q2.x; Qt[d0+ 9][lm] = q2.y; Qt[d0+10][lm] = q2.z; Qt[d0+11][lm] = q2.w;
    Qt[d0+12][lm] = q3.x; Qt[d0+13][lm] = q3.y; Qt[d0+14][lm] = q3.z; Qt[d0+15][lm] = q3.w;
  }
  float acc[4][4] = {};
  float mreg[4] = {-1e30f, -1e30f, -1e30f, -1e30f};
  float lreg[4] = {0.f, 0.f, 0.f, 0.f};
  const bf16_t* kb = k + (size_t)bh * NSEQ * DHEAD;
  const bf16_t* vb = v + (size_t)bh * NSEQ * DHEAD;
  __syncthreads();
  for (int it = 0; it < 64; ++it) {
    int n0 = chunk * 4096 + it * 64;
    {  // stage K,V subtile (64 rows x 64 d, bf16 -> fp32 LDS)
      int jj = tid >> 2, part = tid & 3;
      const uint4* kr = reinterpret_cast<const uint4*>(kb + (size_t)(n0 + jj) * DHEAD);
      uint4 ka = kr[part * 2], ka2 = kr[part * 2 + 1];
      const uint4* vr = reinterpret_cast<const uint4*>(vb + (size_t)(n0 + jj) * DHEAD);
      uint4 va = vr[part * 2], va2 = vr[part * 2 + 1];
      int d0 = part * 16;
      float f0, f1;
      bfpair(ka.x, f0, f1);  Kt[d0+ 0][jj] = f0; Kt[d0+ 1][jj] = f1;
      bfpair(ka.y, f0, f1);  Kt[d0+ 2][jj] = f0; Kt[d0+ 3][jj] = f1;
      bfpair(ka.z, f0, f1);  Kt[d0+ 4][jj] = f0; Kt[d0+ 5][jj] = f1;
      bfpair(ka.w, f0, f1);  Kt[d0+ 6][jj] = f0; Kt[d0+ 7][jj] = f1;
      bfpair(ka2.x, f0, f1); Kt[d0+ 8][jj] = f0; Kt[d0+ 9][jj] = f1;
      bfpair(ka2.y, f0, f1); Kt[d0+10][jj] = f0; Kt[d0+11][jj] = f1;
      bfpair(ka2.z, f0, f1); Kt[d0+12][jj] = f0; Kt[d0+13][jj] = f1;
      bfpair(ka2.w, f0, f1); Kt[d0+14][jj] = f0; Kt[d0+15][jj] = f1;
      bfpair(va.x, f0, f1);  Vs[jj][d0+ 0] = f0; Vs[jj][d0+ 1] = f1;
      bfpair(va.y, f0, f1);  Vs[jj][d0+ 2] = f0; Vs[jj][d0+ 3] = f1;
      bfpair(va.z, f0, f1);  Vs[jj][d0+ 4] = f0; Vs[jj][d0+ 5] = f1;
      bfpair(va.w, f0, f1);  Vs[jj][d0+ 6] = f0; Vs[jj][d0+ 7] = f1;
      bfpair(va2.x, f0, f1); Vs[jj][d0+ 8] = f0; Vs[jj][d0+ 9] = f1;
      bfpair(va2.y, f0, f1); Vs[jj][d0+10] = f0; Vs[jj][d0+11] = f1;
      bfpair(va2.z, f0, f1); Vs[jj][d0+12] = f0; Vs[jj][d0+13] = f1;
      bfpair(va2.w, f0, f1); Vs[jj][d0+14] = f0; Vs[jj][d0+15] = f1;
    }
    __syncthreads();
    // ---- S tile: 4 lm x 4 n per thread ----
    float s[4][4] = {};
    #pragma unroll 16
    for (int dk = 0; dk < 64; ++dk) {
      float4 a4 = *reinterpret_cast<const float4*>(&Qt[dk][ty * 4]);
      float4 b4 = *reinterpret_cast<const float4*>(&Kt[dk][tx * 4]);
      s[0][0] += a4.x*b4.x; s[0][1] += a4.x*b4.y; s[0][2] += a4.x*b4.z; s[0][3] += a4.x*b4.w;
      s[1][0] += a4.y*b4.x; s[1][1] += a4.y*b4.y; s[1][2] += a4.y*b4.z; s[1][3] += a4.y*b4.w;
      s[2][0] += a4.z*b4.x; s[2][1] += a4.z*b4.y; s[2][2] += a4.z*b4.z; s[2][3] += a4.z*b4.w;
      s[3][0] += a4.w*b4.x; s[3][1] += a4.w*b4.y; s[3][2] += a4.w*b4.z; s[3][3] += a4.w*b4.w;
    }
    // ---- online softmax (stats per lm, consistent across the 16 tx lanes) ----
    #pragma unroll
    for (int i = 0; i < 4; ++i) {
      float mt = fmaxf(fmaxf(s[i][0], s[i][1]), fmaxf(s[i][2], s[i][3]));
      #pragma unroll
      for (int off = 1; off < 16; off <<= 1) mt = fmaxf(mt, __shfl_xor(mt, off));
      float mnew = fmaxf(mreg[i], mt);
      float corr = __expf(mreg[i] - mnew);
      float ts = 0.f;
      #pragma unroll
      for (int j = 0; j < 4; ++j) { s[i][j] = __expf(s[i][j] - mnew); ts += s[i][j]; }
      #pragma unroll
      for (int off = 1; off < 16; off <<= 1) ts += __shfl_xor(ts, off);
      lreg[i] = lreg[i] * corr + ts;
      mreg[i] = mnew;
      acc[i][0] *= corr; acc[i][1] *= corr; acc[i][2] *= corr; acc[i][3] *= corr;
    }
    // hand P to (lm,d)-layout threads via LDS transpose
    #pragma unroll
    for (int i = 0; i < 4; ++i)
      #pragma unroll
      for (int j = 0; j < 4; ++j) Pt[tx * 4 + j][ty * 4 + i] = s[i][j];
    __syncthreads();
    // ---- PV: acc[lm][d] += sum_j P[lm][j] * V[j][d] ----
    #pragma unroll 16
    for (int j = 0; j < 64; ++j) {
      float4 p4 = *reinterpret_cast<const float4*>(&Pt[j][ty * 4]);
      float4 v4 = *reinterpret_cast<const float4*>(&Vs[j][tx * 4]);
      acc[0][0] += p4.x*v4.x; acc[0][1] += p4.x*v4.y; acc[0][2] += p4.x*v4.z; acc[0][3] += p4.x*v4.w;
      acc[1][0] += p4.y*v4.x; acc[1][1] += p4.y*v4.y; acc[1][2] += p4.y*v4.z; acc[1][3] += p4.y*v4.w;
      acc[2][0] += p4.z*v4.x; acc[2][1] += p4.z*v4.y; acc[2][2] += p4.z*v4.z; acc[2][3] += p4.z*v4.w;
      acc[3][0] += p4.w*v4.x; acc[3][1] += p4.w*v4.y; acc[3][2] += p4.w*v4.z; acc[3][3] += p4.w*v4.w;
    }
    __syncthreads();
  }
  size_t obase = ((size_t)(chunk * NBH + bh) * NLM + lm0 + ty * 4);
  #pragma unroll
  for (int i = 0; i < 4; ++i) {
    float4 w4 = make_float4(acc[i][0], acc[i][1], acc[i][2], acc[i][3]);
    *reinterpret_cast<float4*>(&Wpart[(obase + i) * DHEAD + tx * 4]) = w4;
  }
  if (tx == 0) {
    #pragma unroll
    for (int i = 0; i < 4; ++i) {
      mlpart[(obase + i) * 2]     = mreg[i];
      mlpart[(obase + i) * 2 + 1] = lreg[i];
    }
  }
}

// combine the 2 n-chunks: W = (W0*e0 + W1*e1) / (l0*e0 + l1*e1)
__global__ void attn3v_combine(const float* __restrict__ Wpart,
    const float* __restrict__ mlpart, float* __restrict__ Wm) {
  int idx = blockIdx.x * 256 + threadIdx.x;  // 524288
  int d = idx & 63;
  int s0 = idx >> 6;                          // bh*256 + lm
  const int CH = NBH * NLM;                   // 8192
  float m0 = mlpart[s0 * 2], l0 = mlpart[s0 * 2 + 1];
  float m1 = mlpart[(CH + s0) * 2], l1 = mlpart[(CH + s0) * 2 + 1];
  float M = fmaxf(m0, m1);
  float e0 = __expf(m0 - M), e1 = __expf(m1 - M);
  float w = Wpart[(size_t)s0 * DHEAD + d] * e0 + Wpart[((size_t)CH + s0) * DHEAD + d] * e1;
  Wm[idx] = w / (l0 * e0 + l1 * e1);
}

// ---------------- U = Z @ W : (256x256)@(256x64) per bh ----------------
__global__ void zw_kernel(const float* __restrict__ z, const float* __restrict__ W,
                          float* __restrict__ U) {
  int idx = blockIdx.x * 256 + threadIdx.x;  // NBH*NLM*DHEAD
  int d = idx & 63, i = (idx >> 6) & 255, bh = idx >> 14;
  const float* zr = z + ((size_t)bh * NLM + i) * NLM;
  const float* Wb = W + (size_t)bh * NLM * DHEAD + d;
  float acc = 0.f;
  for (int j = 0; j < NLM; ++j) acc += zr[j] * Wb[(size_t)j * DHEAD];
  U[idx] = acc;
}

// ---------------- flash attn1: out = softmax(q @ k_l^T) @ U ----------------
// grid (ntile=128, bh=32); per block: 64 q-rows x 4 subtiles of 64 landmarks
__global__ __launch_bounds__(256) void attn1_flash(const bf16_t* __restrict__ q,
    const float* __restrict__ kl, const float* __restrict__ U, bf16_t* __restrict__ outp) {
  __shared__ float Qt[64][68];  // [d][row]
  __shared__ float Kt[64][68];  // [d][lm]
  __shared__ float Us[64][68];  // [lm][d]
  __shared__ float Pt[64][68];  // [lm][row]
  int nt = blockIdx.x, bh = blockIdx.y;
  int tid = threadIdx.x, tx = tid & 15, ty = tid >> 4;
  int n0 = nt * 64;
  {  // stage Q tile (bf16) transposed
    int row = tid >> 2, part = tid & 3;
    const uint4* qr = reinterpret_cast<const uint4*>(
        q + ((size_t)bh * NSEQ + n0 + row) * DHEAD + part * 16);
    uint4 qa = qr[0], qa2 = qr[1];
    int d0 = part * 16;
    float f0, f1;
    bfpair(qa.x, f0, f1);  Qt[d0+ 0][row] = f0; Qt[d0+ 1][row] = f1;
    bfpair(qa.y, f0, f1);  Qt[d0+ 2][row] = f0; Qt[d0+ 3][row] = f1;
    bfpair(qa.z, f0, f1);  Qt[d0+ 4][row] = f0; Qt[d0+ 5][row] = f1;
    bfpair(qa.w, f0, f1);  Qt[d0+ 6][row] = f0; Qt[d0+ 7][row] = f1;
    bfpair(qa2.x, f0, f1); Qt[d0+ 8][row] = f0; Qt[d0+ 9][row] = f1;
    bfpair(qa2.y, f0, f1); Qt[d0+10][row] = f0; Qt[d0+11][row] = f1;
    bfpair(qa2.z, f0, f1); Qt[d0+12][row] = f0; Qt[d0+13][row] = f1;
    bfpair(qa2.w, f0, f1); Qt[d0+14][row] = f0; Qt[d0+15][row] = f1;
  }
  float acc[4][4] = {};
  float mreg[4] = {-1e30f, -1e30f, -1e30f, -1e30f};
  float lreg[4] = {0.f, 0.f, 0.f, 0.f};
  __syncthreads();
  for (int it = 0; it < 4; ++it) {
    int lm0 = it * 64;
    {  // stage kl (transposed) and U subtiles (fp32)
      int jj = tid >> 2, part = tid & 3;
      int d0 = part * 16;
      const float4* kr = reinterpret_cast<const float4*>(
          kl + ((size_t)bh * NLM + lm0 + jj) * DHEAD + d0);
      float4 k0 = kr[0], k1 = kr[1], k2 = kr[2], k3 = kr[3];
      Kt[d0+ 0][jj] = k0.x; Kt[d0+ 1][jj] = k0.y; Kt[d0+ 2][jj] = k0.z; Kt[d0+ 3][jj] = k0.w;
      Kt[d0+ 4][jj] = k1.x; Kt[d0+ 5][jj] = k1.y; Kt[d0+ 6][jj] = k1.z; Kt[d0+ 7][jj] = k1.w;
      Kt[d0+ 8][jj] = k2.x; Kt[d0+ 9][jj] = k2.y; Kt[d0+10][jj] = k2.z; Kt[d0+11][jj] = k2.w;
      Kt[d0+12][jj] = k3.x; Kt[d0+13][jj] = k3.y; Kt[d0+14][jj] = k3.z; Kt[d0+15][jj] = k3.w;
      const float4* ur = reinterpret_cast<const float4*>(
          U + ((size_t)bh * NLM + lm0 + jj) * DHEAD + d0);
      float4* ud = reinterpret_cast<float4*>(&Us[jj][d0]);
      ud[0] = ur[0]; ud[1] = ur[1]; ud[2] = ur[2]; ud[3] = ur[3];
    }
    __syncthreads();
    // ---- S tile: 4 rows x 4 lm per thread ----
    float s[4][4] = {};
    #pragma unroll 16
    for (int dk = 0; dk < 64; ++dk) {
      float4 a4 = *reinterpret_cast<const float4*>(&Qt[dk][ty * 4]);
      float4 b4 = *reinterpret_cast<const float4*>(&Kt[dk][tx * 4]);
      s[0][0] += a4.x*b4.x; s[0][1] += a4.x*b4.y; s[0][2] += a4.x*b4.z; s[0][3] += a4.x*b4.w;
      s[1][0] += a4.y*b4.x; s[1][1] += a4.y*b4.y; s[1][2] += a4.y*b4.z; s[1][3] += a4.y*b4.w;
      s[2][0] += a4.z*b4.x; s[2][1] += a4.z*b4.y; s[2][2] += a4.z*b4.z; s[2][3] += a4.z*b4.w;
      s[3][0] += a4.w*b4.x; s[3][1] += a4.w*b4.y; s[3][2] += a4.w*b4.z; s[3][3] += a4.w*b4.w;
    }
    // ---- online softmax (stats per q-row, consistent across the 16 tx lanes) ----
    #pragma unroll
    for (int i = 0; i < 4; ++i) {
      float mt = fmaxf(fmaxf(s[i][0], s[i][1]), fmaxf(s[i][2], s[i][3]));
      #pragma unroll
      for (int off = 1; off < 16; off <<= 1) mt = fmaxf(mt, __shfl_xor(mt, off));
      float mnew = fmaxf(mreg[i], mt);
      float corr = __expf(mreg[i] - mnew);
      float ts = 0.f;
      #pragma unroll
      for (int j = 0; j < 4; ++j) { s[i][j] = __expf(s[i][j] - mnew); ts += s[i][j]; }
      #pragma unroll
      for (int off = 1; off < 16; off <<= 1) ts += __shfl_xor(ts, off);
      lreg[i] = lreg[i] * corr + ts;
      mreg[i] = mnew;
      acc[i][0] *= corr; acc[i][1] *= corr; acc[i][2] *= corr; acc[i][3] *= corr;
    }
    #pragma unroll
    for (int i = 0; i < 4; ++i)
      #pragma unroll
      for (int j = 0; j < 4; ++j) Pt[tx * 4 + j][ty * 4 + i] = s[i][j];
    __syncthreads();
    // ---- PV: acc[row][d] += sum_j P[row][j] * U[j][d] ----
    #pragma unroll 16
    for (int j = 0; j < 64; ++j) {
      float4 p4 = *reinterpret_cast<const float4*>(&Pt[j][ty * 4]);
      float4 v4 = *reinterpret_cast<const float4*>(&Us[j][tx * 4]);
      acc[0][0] += p4.x*v4.x; acc[0][1] += p4.x*v4.y; acc[0][2] += p4.x*v4.z; acc[0][3] += p4.x*v4.w;
      acc[1][0] += p4.y*v4.x; acc[1][1] += p4.y*v4.y; acc[1][2] += p4.y*v4.z; acc[1][3] += p4.y*v4.w;
      acc[2][0] += p4.z*v4.x; acc[2][1] += p4.z*v4.y; acc[2][2] += p4.z*v4.z; acc[2][3] += p4.z*v4.w;
      acc[3][0] += p4.w*v4.x; acc[3][1] += p4.w*v4.y; acc[3][2] += p4.w*v4.z; acc[3][3] += p4.w*v4.w;
    }
    __syncthreads();
  }
  int b = bh >> 3, h = bh & 7;
  #pragma unroll
  for (int i = 0; i < 4; ++i) {
    float inv = 1.0f / lreg[i];
    int n = n0 + ty * 4 + i;
    ushort4 o;
    o.x = f2bf(acc[i][0] * inv); o.y = f2bf(acc[i][1] * inv);
    o.z = f2bf(acc[i][2] * inv); o.w = f2bf(acc[i][3] * inv);
    *reinterpret_cast<ushort4*>(
        &outp[((size_t)(b * NSEQ + n)) * DMODEL + h * DHEAD + tx * 4]) = o;
  }
}

// ---------------- depthwise conv residual, added into bf16 out_pre ----------------
__global__ void conv_kernel(const bf16_t* __restrict__ v, const float* __restrict__ rk,
                            bf16_t* __restrict__ outp) {
  int idx = blockIdx.x * 256 + threadIdx.x;  // NB*NSEQ*DMODEL
  int d = idx & 63, h = (idx >> 6) & 7, n = (idx >> 9) & 8191, b = idx >> 22;
  const bf16_t* vb = v + ((size_t)(b * NHEADS + h) * NSEQ) * DHEAD + d;
  const float* wk = rk + h * KCONV;
  float acc = 0.f;
  #pragma unroll
  for (int tp = 0; tp < KCONV; ++tp) {
    int nn = n + tp - 16;
    if (nn >= 0 && nn < NSEQ) acc += bf2f(vb[(size_t)nn * DHEAD]) * wk[tp];
  }
  outp[idx] = f2bf(bf2f(outp[idx]) + acc);
}

// ---------------- final: y = x + out_pre @ w_out + b_out ----------------
__global__ __launch_bounds__(256) void gemm_out(const bf16_t* __restrict__ A,
    const float* __restrict__ Bm, const float* __restrict__ bo,
    const float* __restrict__ x, float* __restrict__ y) {
  __shared__ float As[16][68];
  __shared__ float Bs[16][68];
  int rowB = blockIdx.x * 64, colB = blockIdx.y * 64;
  int tid = threadIdx.x, tx = tid & 15, ty = tid >> 4;
  float acc[4][4] = {};
  for (int k0 = 0; k0 < DMODEL; k0 += 16) {
    {
      int row = tid >> 2, quad = tid & 3;
      const ushort4 a4 = *reinterpret_cast<const ushort4*>(
          A + (size_t)(rowB + row) * DMODEL + k0 + quad * 4);
      As[quad * 4 + 0][row] = bf2f(a4.x);
      As[quad * 4 + 1][row] = bf2f(a4.y);
      As[quad * 4 + 2][row] = bf2f(a4.z);
      As[quad * 4 + 3][row] = bf2f(a4.w);
    }
    #pragma unroll
    for (int i = 0; i < 4; ++i) {
      int idx = tid + i * 256;
      Bs[idx >> 6][idx & 63] = Bm[(size_t)(k0 + (idx >> 6)) * DMODEL + colB + (idx & 63)];
    }
    __syncthreads();
    #pragma unroll
    for (int kk = 0; kk < 16; ++kk) {
      float4 a4 = *reinterpret_cast<const float4*>(&As[kk][ty * 4]);
      float4 b4 = *reinterpret_cast<const float4*>(&Bs[kk][tx * 4]);
      acc[0][0] += a4.x*b4.x; acc[0][1] += a4.x*b4.y; acc[0][2] += a4.x*b4.z; acc[0][3] += a4.x*b4.w;
      acc[1][0] += a4.y*b4.x; acc[1][1] += a4.y*b4.y; acc[1][2] += a4.y*b4.z; acc[1][3] += a4.y*b4.w;
      acc[2][0] += a4.z*b4.x; acc[2][1] += a4.z*b4.y; acc[2][2] += a4.z*b4.z; acc[2][3] += a4.z*b4.w;
      acc[3][0] += a4.w*b4.x; acc[3][1] += a4.w*b4.y; acc[3][2] += a4.w*b4.z; acc[3][3] += a4.w*b4.w;
    }
    __syncthreads();
  }
  #pragma unroll
  for (int i = 0; i < 4; ++i) {
    int r = rowB + ty * 4 + i;
    #pragma unroll
    for (int j = 0; j < 4; ++j) {
      int c = colB + tx * 4 + j;
      y[(size_t)r * DMODEL + c] = x[(size_t)r * DMODEL + c] + bo[c] + acc[i][j];
    }
  }
}

extern "C" void kernel_launch(void* const* d_in, const int* in_sizes, int n_in,
                              void* d_out, int out_size, void* d_ws, size_t ws_size,
                              hipStream_t stream) {
  const float* x     = (const float*)d_in[0];
  const float* gamma = (const float*)d_in[1];
  const float* beta  = (const float*)d_in[2];
  const float* wqkv  = (const float*)d_in[3];
  const float* wout  = (const float*)d_in[4];
  const float* bout  = (const float*)d_in[5];
  const float* rk    = (const float*)d_in[6];
  float* y = (float*)d_out;

  // ---- workspace layout: 176 MB + 8 B total ----
  char* wsb = (char*)d_ws;
  bf16_t* xn = (bf16_t*)(wsb);                   // 32 MB, reused as out_pre
  bf16_t* q  = (bf16_t*)(wsb + 33554432ull);     // 32 MB
  bf16_t* k  = (bf16_t*)(wsb + 67108864ull);     // 32 MB
  bf16_t* v  = (bf16_t*)(wsb + 100663296ull);    // 32 MB
  float* a2  = (float*)(wsb + 134217728ull);     // 8 MB
  float* z   = (float*)(wsb + 142606336ull);     // 8 MB
  float* az  = (float*)(wsb + 150994944ull);     // 8 MB (dead after pinv -> Wpart)
  float* t1  = (float*)(wsb + 159383552ull);     // 8 MB (dead after pinv -> mlpart)
  float* t2  = (float*)(wsb + 167772160ull);     // 8 MB
  float* ql  = (float*)(wsb + 176160768ull);     // 2 MB
  float* kl  = (float*)(wsb + 178257920ull);     // 2 MB
  float* Wm  = (float*)(wsb + 180355072ull);     // 2 MB
  float* Um  = (float*)(wsb + 182452224ull);     // 2 MB
  unsigned int* scal = (unsigned int*)(wsb + 184549376ull);  // 8 B

  ln_kernel<<<8192, 256, 0, stream>>>(x, gamma, beta, xn);
  gemm_qkv<<<dim3(512, 24), 256, 0, stream>>>(xn, wqkv, q, k, v);
  pool_kernel<<<4096, 256, 0, stream>>>(q, k, ql, kl);
  attn2_kernel<<<dim3(256, 32), 256, 0, stream>>>(ql, kl, a2);
  zero2_kernel<<<1, 64, 0, stream>>>(scal);
  colrow_kernel<<<64, 256, 0, stream>>>(a2, scal);
  zinit_kernel<<<8192, 256, 0, stream>>>(a2, scal, z);

  float *pz = z, *paz = az, *pt1 = t1, *pt2 = t2;
  for (int it = 0; it < 6; ++it) {
    matmul256<<<dim3(16, 32), 256, 0, stream>>>(paz, a2, pz, 0.f, -1.f);   // az = a@z
    matmul256<<<dim3(16, 32), 256, 0, stream>>>(pt2, paz, paz, 7.f, 1.f);  // t2 = 7*az - az@az
    matmul256<<<dim3(16, 32), 256, 0, stream>>>(pt1, paz, pt2, 15.f, 1.f); // t1 = 15*az - az@t2
    matmul256<<<dim3(16, 32), 256, 0, stream>>>(pt2, pz, pt1, 13.f, 0.25f);// z' = .25*(13z - z@t1)
    float* tmp = pz; pz = pt2; pt2 = tmp;
  }
  // after 6 swaps pz == z; az/t1/t2/a2 are dead -> reuse for flash partials
  float* Wpart  = az;   // 2*32*256*64 fp32 = 4 MB
  float* mlpart = t1;   // 2*32*256*2 fp32 = 128 KB

  attn3v_flash<<<dim3(2, 4, 32), 256, 0, stream>>>(ql, k, v, Wpart, mlpart);
  attn3v_combine<<<2048, 256, 0, stream>>>(Wpart, mlpart, Wm);
  zw_kernel<<<2048, 256, 0, stream>>>(pz, Wm, Um);
  attn1_flash<<<dim3(128, 32), 256, 0, stream>>>(q, kl, Um, xn /*out_pre*/);
  conv_kernel<<<65536, 256, 0, stream>>>(v, rk, xn);
  gemm_out<<<dim3(512, 8), 256, 0, stream>>>(xn, wout, bout, x, y);
}

// Round 5
// 1759.272 us; speedup vs baseline: 4.8026x; 1.4008x over previous
//
#include <hip/hip_runtime.h>
#include <math.h>

#define NB 4
#define NSEQ 8192
#define DMODEL 512
#define NHEADS 8
#define DHEAD 64
#define NLM 256
#define LTOK 32
#define NBH 32
#define KCONV 33

typedef unsigned short bf16_t;
typedef __attribute__((ext_vector_type(8))) short bf16x8;
typedef __attribute__((ext_vector_type(4))) float f32x4;

__device__ __forceinline__ float bf2f(bf16_t u) {
  return __uint_as_float(((unsigned)u) << 16);
}
__device__ __forceinline__ bf16_t f2bf(float f) {
  unsigned u = __float_as_uint(f);
  return (bf16_t)((u + 0x7fffu + ((u >> 16) & 1u)) >> 16);  // RTNE
}
__device__ __forceinline__ void bfpair(unsigned u, float& lo, float& hi) {
  lo = __uint_as_float(u << 16);
  hi = __uint_as_float(u & 0xffff0000u);
}

// ---------------- LayerNorm: one wave per 512-float row, bf16 out ----------------
__global__ __launch_bounds__(256) void ln_kernel(const float* __restrict__ x,
    const float* __restrict__ gamma, const float* __restrict__ beta,
    bf16_t* __restrict__ xn) {
  int row = blockIdx.x * 4 + (threadIdx.x >> 6);
  int lane = threadIdx.x & 63;
  const float4* xr = reinterpret_cast<const float4*>(x + (size_t)row * DMODEL);
  float4 a0 = xr[lane];
  float4 a1 = xr[lane + 64];
  float s  = a0.x + a0.y + a0.z + a0.w + a1.x + a1.y + a1.z + a1.w;
  float s2 = a0.x*a0.x + a0.y*a0.y + a0.z*a0.z + a0.w*a0.w
           + a1.x*a1.x + a1.y*a1.y + a1.z*a1.z + a1.w*a1.w;
  #pragma unroll
  for (int off = 32; off; off >>= 1) {
    s  += __shfl_down(s, off);
    s2 += __shfl_down(s2, off);
  }
  s = __shfl(s, 0); s2 = __shfl(s2, 0);
  float mu = s * (1.0f / DMODEL);
  float var = s2 * (1.0f / DMODEL) - mu * mu;
  float rs = rsqrtf(var + 1e-5f);
  const float4* g4 = reinterpret_cast<const float4*>(gamma);
  const float4* b4 = reinterpret_cast<const float4*>(beta);
  float4 g0 = g4[lane], g1 = g4[lane + 64];
  float4 bb0 = b4[lane], bb1 = b4[lane + 64];
  ushort4 o0, o1;
  o0.x = f2bf((a0.x - mu) * rs * g0.x + bb0.x);
  o0.y = f2bf((a0.y - mu) * rs * g0.y + bb0.y);
  o0.z = f2bf((a0.z - mu) * rs * g0.z + bb0.z);
  o0.w = f2bf((a0.w - mu) * rs * g0.w + bb0.w);
  o1.x = f2bf((a1.x - mu) * rs * g1.x + bb1.x);
  o1.y = f2bf((a1.y - mu) * rs * g1.y + bb1.y);
  o1.z = f2bf((a1.z - mu) * rs * g1.z + bb1.z);
  o1.w = f2bf((a1.w - mu) * rs * g1.w + bb1.w);
  ushort4* o = reinterpret_cast<ushort4*>(xn + (size_t)row * DMODEL);
  o[lane] = o0; o[lane + 64] = o1;
}

// ---------------- transpose-cast fp32 weight [512][N] -> bf16 [N][512] ----------------
__global__ void castT_kernel(const float* __restrict__ in, bf16_t* __restrict__ outp, int N) {
  int idx = blockIdx.x * 256 + threadIdx.x;  // N*512 total
  int k = idx & 511, c = idx >> 9;
  outp[idx] = f2bf(in[(size_t)k * N + c]);
}

// ---------------- MFMA QKV GEMM: (32768x512)@(512x1536), NT layout ----------------
// A: xn bf16 row-major [32768][512]; Bt: wqkvT bf16 [1536][512]
__global__ __launch_bounds__(256) void gemm_qkv_mfma(const bf16_t* __restrict__ A,
    const bf16_t* __restrict__ Bt, bf16_t* __restrict__ q, bf16_t* __restrict__ k,
    bf16_t* __restrict__ v) {
  __shared__ __align__(16) bf16_t As[128][40];
  __shared__ __align__(16) bf16_t Bs[128][40];
  int rowB = blockIdx.x * 128, colB = blockIdx.y * 128;
  int tid = threadIdx.x;
  int wave = tid >> 6, lane = tid & 63;
  int wr = (wave >> 1) * 64, wc = (wave & 1) * 64;
  int lrow = lane & 15, g = lane >> 4;
  int srow = tid >> 1, shalf = tid & 1;
  f32x4 acc[4][4] = {};
  for (int k0 = 0; k0 < DMODEL; k0 += 32) {
    {
      const uint4* ap = reinterpret_cast<const uint4*>(
          A + (size_t)(rowB + srow) * DMODEL + k0 + shalf * 16);
      uint4 a0 = ap[0], a1 = ap[1];
      *reinterpret_cast<uint4*>(&As[srow][shalf * 16]) = a0;
      *reinterpret_cast<uint4*>(&As[srow][shalf * 16 + 8]) = a1;
      const uint4* bp = reinterpret_cast<const uint4*>(
          Bt + (size_t)(colB + srow) * DMODEL + k0 + shalf * 16);
      uint4 b0 = bp[0], b1 = bp[1];
      *reinterpret_cast<uint4*>(&Bs[srow][shalf * 16]) = b0;
      *reinterpret_cast<uint4*>(&Bs[srow][shalf * 16 + 8]) = b1;
    }
    __syncthreads();
    bf16x8 af[4], bf[4];
    #pragma unroll
    for (int m = 0; m < 4; ++m)
      af[m] = *reinterpret_cast<const bf16x8*>(&As[wr + m * 16 + lrow][g * 8]);
    #pragma unroll
    for (int n = 0; n < 4; ++n)
      bf[n] = *reinterpret_cast<const bf16x8*>(&Bs[wc + n * 16 + lrow][g * 8]);
    #pragma unroll
    for (int m = 0; m < 4; ++m)
      #pragma unroll
      for (int n = 0; n < 4; ++n)
        acc[m][n] = __builtin_amdgcn_mfma_f32_16x16x32_bf16(af[m], bf[n], acc[m][n], 0, 0, 0);
    __syncthreads();
  }
  #pragma unroll
  for (int m = 0; m < 4; ++m) {
    #pragma unroll
    for (int n = 0; n < 4; ++n) {
      int col = colB + wc + n * 16 + lrow;
      int which = col >> 9, hc = col & 511, h = hc >> 6, d = hc & 63;
      bf16_t* dst = (which == 0) ? q : (which == 1 ? k : v);
      float scale = (which == 0) ? 0.125f : 1.0f;
      #pragma unroll
      for (int r = 0; r < 4; ++r) {
        int row = rowB + wr + m * 16 + g * 4 + r;
        int b = row >> 13, nn = row & 8191;
        dst[((size_t)(b * NHEADS + h) * NSEQ + nn) * DHEAD + d] = f2bf(acc[m][n][r] * scale);
      }
    }
  }
}

// ---------------- MFMA out GEMM: y = x + out_pre @ w_out + b_out ----------------
// A: out_pre bf16 [32768][512]; Bt: woutT bf16 [512][512]
__global__ __launch_bounds__(256) void gemm_out_mfma(const bf16_t* __restrict__ A,
    const bf16_t* __restrict__ Bt, const float* __restrict__ bo,
    const float* __restrict__ x, float* __restrict__ y) {
  __shared__ __align__(16) bf16_t As[128][40];
  __shared__ __align__(16) bf16_t Bs[128][40];
  int rowB = blockIdx.x * 128, colB = blockIdx.y * 128;
  int tid = threadIdx.x;
  int wave = tid >> 6, lane = tid & 63;
  int wr = (wave >> 1) * 64, wc = (wave & 1) * 64;
  int lrow = lane & 15, g = lane >> 4;
  int srow = tid >> 1, shalf = tid & 1;
  f32x4 acc[4][4] = {};
  for (int k0 = 0; k0 < DMODEL; k0 += 32) {
    {
      const uint4* ap = reinterpret_cast<const uint4*>(
          A + (size_t)(rowB + srow) * DMODEL + k0 + shalf * 16);
      uint4 a0 = ap[0], a1 = ap[1];
      *reinterpret_cast<uint4*>(&As[srow][shalf * 16]) = a0;
      *reinterpret_cast<uint4*>(&As[srow][shalf * 16 + 8]) = a1;
      const uint4* bp = reinterpret_cast<const uint4*>(
          Bt + (size_t)(colB + srow) * DMODEL + k0 + shalf * 16);
      uint4 b0 = bp[0], b1 = bp[1];
      *reinterpret_cast<uint4*>(&Bs[srow][shalf * 16]) = b0;
      *reinterpret_cast<uint4*>(&Bs[srow][shalf * 16 + 8]) = b1;
    }
    __syncthreads();
    bf16x8 af[4], bf[4];
    #pragma unroll
    for (int m = 0; m < 4; ++m)
      af[m] = *reinterpret_cast<const bf16x8*>(&As[wr + m * 16 + lrow][g * 8]);
    #pragma unroll
    for (int n = 0; n < 4; ++n)
      bf[n] = *reinterpret_cast<const bf16x8*>(&Bs[wc + n * 16 + lrow][g * 8]);
    #pragma unroll
    for (int m = 0; m < 4; ++m)
      #pragma unroll
      for (int n = 0; n < 4; ++n)
        acc[m][n] = __builtin_amdgcn_mfma_f32_16x16x32_bf16(af[m], bf[n], acc[m][n], 0, 0, 0);
    __syncthreads();
  }
  #pragma unroll
  for (int m = 0; m < 4; ++m) {
    #pragma unroll
    for (int n = 0; n < 4; ++n) {
      int col = colB + wc + n * 16 + lrow;
      float bias = bo[col];
      #pragma unroll
      for (int r = 0; r < 4; ++r) {
        int row = rowB + wr + m * 16 + g * 4 + r;
        size_t off = (size_t)row * DMODEL + col;
        y[off] = x[off] + bias + acc[m][n][r];
      }
    }
  }
}

// ---------------- landmark mean pooling (q and k), fp32 out ----------------
__global__ void pool_kernel(const bf16_t* __restrict__ q, const bf16_t* __restrict__ k,
                            float* __restrict__ ql, float* __restrict__ kl) {
  int idx = blockIdx.x * 256 + threadIdx.x;  // 2 * 524288
  const int half = NBH * NLM * DHEAD;
  const bf16_t* src = (idx < half) ? q : k;
  float* dst = (idx < half) ? ql : kl;
  int i = (idx < half) ? idx : idx - half;
  int d = i & 63, m = (i >> 6) & 255, bh = i >> 14;
  const bf16_t* p = src + ((size_t)bh * NSEQ + m * LTOK) * DHEAD + d;
  float sum = 0.f;
  #pragma unroll
  for (int t = 0; t < LTOK; ++t) sum += bf2f(p[(size_t)t * DHEAD]);
  dst[i] = sum * (1.0f / LTOK);
}

// ---------------- attn2 = softmax(q_l @ k_l^T), 256x256 per bh ----------------
__global__ __launch_bounds__(256) void attn2_kernel(const float* __restrict__ ql,
    const float* __restrict__ kl, float* __restrict__ a2) {
  __shared__ float qs[64];
  __shared__ float red[256];
  int bh = blockIdx.y, i = blockIdx.x, t = threadIdx.x;
  if (t < 64) qs[t] = ql[((size_t)bh * NLM + i) * DHEAD + t];
  __syncthreads();
  const float* kr = kl + ((size_t)bh * NLM + t) * DHEAD;
  float s = 0.f;
  #pragma unroll
  for (int d = 0; d < 64; ++d) s += qs[d] * kr[d];
  red[t] = s; __syncthreads();
  for (int off = 128; off; off >>= 1) { if (t < off) red[t] = fmaxf(red[t], red[t + off]); __syncthreads(); }
  float mx = red[0]; __syncthreads();
  float p = expf(s - mx);
  red[t] = p; __syncthreads();
  for (int off = 128; off; off >>= 1) { if (t < off) red[t] += red[t + off]; __syncthreads(); }
  a2[((size_t)bh * NLM + i) * NLM + t] = p / red[0];
}

__global__ void zero2_kernel(unsigned int* __restrict__ scal) {
  if (threadIdx.x < 2) scal[threadIdx.x] = 0u;
}

// ---------------- global col/row maxima for pinv init ----------------
__global__ void colrow_kernel(const float* __restrict__ a2, unsigned int* __restrict__ scal) {
  int bh = blockIdx.x & 31, mode = blockIdx.x >> 5;
  int t = threadIdx.x;
  const float* Ab = a2 + (size_t)bh * NLM * NLM;
  float sum = 0.f;
  if (mode == 0) { for (int j = 0; j < NLM; ++j) sum += fabsf(Ab[(size_t)t * NLM + j]); }
  else           { for (int i2 = 0; i2 < NLM; ++i2) sum += fabsf(Ab[(size_t)i2 * NLM + t]); }
  __shared__ float red[256];
  red[t] = sum; __syncthreads();
  for (int off = 128; off; off >>= 1) { if (t < off) red[t] = fmaxf(red[t], red[t + off]); __syncthreads(); }
  if (t == 0) atomicMax(&scal[mode], __float_as_uint(red[0]));  // all values > 0
}

// ---------------- z0 = a^T / (col*row) ----------------
__global__ void zinit_kernel(const float* __restrict__ a2, const unsigned int* __restrict__ scal,
                             float* __restrict__ z) {
  int idx = blockIdx.x * 256 + threadIdx.x;  // 2097152
  float inv = 1.0f / (__uint_as_float(scal[0]) * __uint_as_float(scal[1]));
  int j = idx & 255, i = (idx >> 8) & 255, bh = idx >> 16;
  z[idx] = a2[((size_t)bh * NLM + j) * NLM + i] * inv;
}

// ---------------- batched 256x256 matmul: C = alpha*(s*A - A@B) per bh ----------------
__global__ __launch_bounds__(256) void matmul256(float* __restrict__ C,
    const float* __restrict__ A, const float* __restrict__ Bm, float s, float alpha) {
  __shared__ float As[16][68];
  __shared__ float Bs[16][68];
  int bh = blockIdx.y;
  const float* Ab = A + (size_t)bh * NLM * NLM;
  const float* Bb = Bm + (size_t)bh * NLM * NLM;
  float* Cb = C + (size_t)bh * NLM * NLM;
  int rowB = (blockIdx.x >> 2) * 64, colB = (blockIdx.x & 3) * 64;
  int tid = threadIdx.x, tx = tid & 15, ty = tid >> 4;
  float acc[4][4] = {};
  for (int k0 = 0; k0 < NLM; k0 += 16) {
    #pragma unroll
    for (int i = 0; i < 4; ++i) {
      int idx = tid + i * 256;
      As[idx & 15][idx >> 4] = Ab[(size_t)(rowB + (idx >> 4)) * NLM + k0 + (idx & 15)];
    }
    #pragma unroll
    for (int i = 0; i < 4; ++i) {
      int idx = tid + i * 256;
      Bs[idx >> 6][idx & 63] = Bb[(size_t)(k0 + (idx >> 6)) * NLM + colB + (idx & 63)];
    }
    __syncthreads();
    #pragma unroll
    for (int kk = 0; kk < 16; ++kk) {
      float4 a4 = *reinterpret_cast<const float4*>(&As[kk][ty * 4]);
      float4 b4 = *reinterpret_cast<const float4*>(&Bs[kk][tx * 4]);
      acc[0][0] += a4.x*b4.x; acc[0][1] += a4.x*b4.y; acc[0][2] += a4.x*b4.z; acc[0][3] += a4.x*b4.w;
      acc[1][0] += a4.y*b4.x; acc[1][1] += a4.y*b4.y; acc[1][2] += a4.y*b4.z; acc[1][3] += a4.y*b4.w;
      acc[2][0] += a4.z*b4.x; acc[2][1] += a4.z*b4.y; acc[2][2] += a4.z*b4.z; acc[2][3] += a4.z*b4.w;
      acc[3][0] += a4.w*b4.x; acc[3][1] += a4.w*b4.y; acc[3][2] += a4.w*b4.z; acc[3][3] += a4.w*b4.w;
    }
    __syncthreads();
  }
  #pragma unroll
  for (int i = 0; i < 4; ++i) {
    int r = rowB + ty * 4 + i;
    #pragma unroll
    for (int j = 0; j < 4; ++j) {
      int c = colB + tx * 4 + j;
      float aij = (s != 0.0f) ? Ab[(size_t)r * NLM + c] : 0.0f;
      Cb[(size_t)r * NLM + c] = alpha * (s * aij - acc[i][j]);
    }
  }
}

// ---------------- flash attn3@v: W_part = softmax-partial(q_l @ k^T) @ v ----------------
__global__ __launch_bounds__(256) void attn3v_flash(const float* __restrict__ ql,
    const bf16_t* __restrict__ k, const bf16_t* __restrict__ v,
    float* __restrict__ Wpart, float* __restrict__ mlpart) {
  __shared__ float Qt[64][68];  // [d][lm]
  __shared__ float Kt[64][68];  // [d][n]
  __shared__ float Vs[64][68];  // [n][d]
  __shared__ float Pt[64][68];  // [n][lm]
  int chunk = blockIdx.x, lmt = blockIdx.y, bh = blockIdx.z;
  int tid = threadIdx.x, tx = tid & 15, ty = tid >> 4;
  int lm0 = lmt * 64;
  {
    int lm = tid >> 2, part = tid & 3;
    const float4* qr = reinterpret_cast<const float4*>(
        ql + ((size_t)bh * NLM + lm0 + lm) * DHEAD + part * 16);
    float4 q0 = qr[0], q1 = qr[1], q2 = qr[2], q3 = qr[3];
    int d0 = part * 16;
    Qt[d0+ 0][lm] = q0.x; Qt[d0+ 1][lm] = q0.y; Qt[d0+ 2][lm] = q0.z; Qt[d0+ 3][lm] = q0.w;
    Qt[d0+ 4][lm] = q1.x; Qt[d0+ 5][lm] = q1.y; Qt[d0+ 6][lm] = q1.z; Qt[d0+ 7][lm] = q1.w;
    Qt[d0+ 8][lm] = q2.x; Qt[d0+ 9][lm] = q2.y; Qt[d0+10][lm] = q2.z; Qt[d0+11][lm] = q2.w;
    Qt[d0+12][lm] = q3.x; Qt[d0+13][lm] = q3.y; Qt[d0+14][lm] = q3.z; Qt[d0+15][lm] = q3.w;
  }
  float acc[4][4] = {};
  float mreg[4] = {-1e30f, -1e30f, -1e30f, -1e30f};
  float lreg[4] = {0.f, 0.f, 0.f, 0.f};
  const bf16_t* kb = k + (size_t)bh * NSEQ * DHEAD;
  const bf16_t* vb = v + (size_t)bh * NSEQ * DHEAD;
  __syncthreads();
  for (int it = 0; it < 64; ++it) {
    int n0 = chunk * 4096 + it * 64;
    {
      int jj = tid >> 2, part = tid & 3;
      const uint4* kr = reinterpret_cast<const uint4*>(kb + (size_t)(n0 + jj) * DHEAD);
      uint4 ka = kr[part * 2], ka2 = kr[part * 2 + 1];
      const uint4* vr = reinterpret_cast<const uint4*>(vb + (size_t)(n0 + jj) * DHEAD);
      uint4 va = vr[part * 2], va2 = vr[part * 2 + 1];
      int d0 = part * 16;
      float f0, f1;
      bfpair(ka.x, f0, f1);  Kt[d0+ 0][jj] = f0; Kt[d0+ 1][jj] = f1;
      bfpair(ka.y, f0, f1);  Kt[d0+ 2][jj] = f0; Kt[d0+ 3][jj] = f1;
      bfpair(ka.z, f0, f1);  Kt[d0+ 4][jj] = f0; Kt[d0+ 5][jj] = f1;
      bfpair(ka.w, f0, f1);  Kt[d0+ 6][jj] = f0; Kt[d0+ 7][jj] = f1;
      bfpair(ka2.x, f0, f1); Kt[d0+ 8][jj] = f0; Kt[d0+ 9][jj] = f1;
      bfpair(ka2.y, f0, f1); Kt[d0+10][jj] = f0; Kt[d0+11][jj] = f1;
      bfpair(ka2.z, f0, f1); Kt[d0+12][jj] = f0; Kt[d0+13][jj] = f1;
      bfpair(ka2.w, f0, f1); Kt[d0+14][jj] = f0; Kt[d0+15][jj] = f1;
      bfpair(va.x, f0, f1);  Vs[jj][d0+ 0] = f0; Vs[jj][d0+ 1] = f1;
      bfpair(va.y, f0, f1);  Vs[jj][d0+ 2] = f0; Vs[jj][d0+ 3] = f1;
      bfpair(va.z, f0, f1);  Vs[jj][d0+ 4] = f0; Vs[jj][d0+ 5] = f1;
      bfpair(va.w, f0, f1);  Vs[jj][d0+ 6] = f0; Vs[jj][d0+ 7] = f1;
      bfpair(va2.x, f0, f1); Vs[jj][d0+ 8] = f0; Vs[jj][d0+ 9] = f1;
      bfpair(va2.y, f0, f1); Vs[jj][d0+10] = f0; Vs[jj][d0+11] = f1;
      bfpair(va2.z, f0, f1); Vs[jj][d0+12] = f0; Vs[jj][d0+13] = f1;
      bfpair(va2.w, f0, f1); Vs[jj][d0+14] = f0; Vs[jj][d0+15] = f1;
    }
    __syncthreads();
    float s[4][4] = {};
    #pragma unroll 16
    for (int dk = 0; dk < 64; ++dk) {
      float4 a4 = *reinterpret_cast<const float4*>(&Qt[dk][ty * 4]);
      float4 b4 = *reinterpret_cast<const float4*>(&Kt[dk][tx * 4]);
      s[0][0] += a4.x*b4.x; s[0][1] += a4.x*b4.y; s[0][2] += a4.x*b4.z; s[0][3] += a4.x*b4.w;
      s[1][0] += a4.y*b4.x; s[1][1] += a4.y*b4.y; s[1][2] += a4.y*b4.z; s[1][3] += a4.y*b4.w;
      s[2][0] += a4.z*b4.x; s[2][1] += a4.z*b4.y; s[2][2] += a4.z*b4.z; s[2][3] += a4.z*b4.w;
      s[3][0] += a4.w*b4.x; s[3][1] += a4.w*b4.y; s[3][2] += a4.w*b4.z; s[3][3] += a4.w*b4.w;
    }
    #pragma unroll
    for (int i = 0; i < 4; ++i) {
      float mt = fmaxf(fmaxf(s[i][0], s[i][1]), fmaxf(s[i][2], s[i][3]));
      #pragma unroll
      for (int off = 1; off < 16; off <<= 1) mt = fmaxf(mt, __shfl_xor(mt, off));
      float mnew = fmaxf(mreg[i], mt);
      float corr = __expf(mreg[i] - mnew);
      float ts = 0.f;
      #pragma unroll
      for (int j = 0; j < 4; ++j) { s[i][j] = __expf(s[i][j] - mnew); ts += s[i][j]; }
      #pragma unroll
      for (int off = 1; off < 16; off <<= 1) ts += __shfl_xor(ts, off);
      lreg[i] = lreg[i] * corr + ts;
      mreg[i] = mnew;
      acc[i][0] *= corr; acc[i][1] *= corr; acc[i][2] *= corr; acc[i][3] *= corr;
    }
    #pragma unroll
    for (int i = 0; i < 4; ++i)
      #pragma unroll
      for (int j = 0; j < 4; ++j) Pt[tx * 4 + j][ty * 4 + i] = s[i][j];
    __syncthreads();
    #pragma unroll 16
    for (int j = 0; j < 64; ++j) {
      float4 p4 = *reinterpret_cast<const float4*>(&Pt[j][ty * 4]);
      float4 v4 = *reinterpret_cast<const float4*>(&Vs[j][tx * 4]);
      acc[0][0] += p4.x*v4.x; acc[0][1] += p4.x*v4.y; acc[0][2] += p4.x*v4.z; acc[0][3] += p4.x*v4.w;
      acc[1][0] += p4.y*v4.x; acc[1][1] += p4.y*v4.y; acc[1][2] += p4.y*v4.z; acc[1][3] += p4.y*v4.w;
      acc[2][0] += p4.z*v4.x; acc[2][1] += p4.z*v4.y; acc[2][2] += p4.z*v4.z; acc[2][3] += p4.z*v4.w;
      acc[3][0] += p4.w*v4.x; acc[3][1] += p4.w*v4.y; acc[3][2] += p4.w*v4.z; acc[3][3] += p4.w*v4.w;
    }
    __syncthreads();
  }
  size_t obase = ((size_t)(chunk * NBH + bh) * NLM + lm0 + ty * 4);
  #pragma unroll
  for (int i = 0; i < 4; ++i) {
    float4 w4 = make_float4(acc[i][0], acc[i][1], acc[i][2], acc[i][3]);
    *reinterpret_cast<float4*>(&Wpart[(obase + i) * DHEAD + tx * 4]) = w4;
  }
  if (tx == 0) {
    #pragma unroll
    for (int i = 0; i < 4; ++i) {
      mlpart[(obase + i) * 2]     = mreg[i];
      mlpart[(obase + i) * 2 + 1] = lreg[i];
    }
  }
}

// combine the 2 n-chunks
__global__ void attn3v_combine(const float* __restrict__ Wpart,
    const float* __restrict__ mlpart, float* __restrict__ Wm) {
  int idx = blockIdx.x * 256 + threadIdx.x;  // 524288
  int d = idx & 63;
  int s0 = idx >> 6;
  const int CH = NBH * NLM;
  float m0 = mlpart[s0 * 2], l0 = mlpart[s0 * 2 + 1];
  float m1 = mlpart[(CH + s0) * 2], l1 = mlpart[(CH + s0) * 2 + 1];
  float M = fmaxf(m0, m1);
  float e0 = __expf(m0 - M), e1 = __expf(m1 - M);
  float w = Wpart[(size_t)s0 * DHEAD + d] * e0 + Wpart[((size_t)CH + s0) * DHEAD + d] * e1;
  Wm[idx] = w / (l0 * e0 + l1 * e1);
}

// ---------------- U = Z @ W : (256x256)@(256x64) per bh ----------------
__global__ void zw_kernel(const float* __restrict__ z, const float* __restrict__ W,
                          float* __restrict__ U) {
  int idx = blockIdx.x * 256 + threadIdx.x;
  int d = idx & 63, i = (idx >> 6) & 255, bh = idx >> 14;
  const float* zr = z + ((size_t)bh * NLM + i) * NLM;
  const float* Wb = W + (size_t)bh * NLM * DHEAD + d;
  float acc = 0.f;
  for (int j = 0; j < NLM; ++j) acc += zr[j] * Wb[(size_t)j * DHEAD];
  U[idx] = acc;
}

// ---------------- flash attn1: out = softmax(q @ k_l^T) @ U ----------------
__global__ __launch_bounds__(256) void attn1_flash(const bf16_t* __restrict__ q,
    const float* __restrict__ kl, const float* __restrict__ U, bf16_t* __restrict__ outp) {
  __shared__ float Qt[64][68];
  __shared__ float Kt[64][68];
  __shared__ float Us[64][68];
  __shared__ float Pt[64][68];
  int nt = blockIdx.x, bh = blockIdx.y;
  int tid = threadIdx.x, tx = tid & 15, ty = tid >> 4;
  int n0 = nt * 64;
  {
    int row = tid >> 2, part = tid & 3;
    const uint4* qr = reinterpret_cast<const uint4*>(
        q + ((size_t)bh * NSEQ + n0 + row) * DHEAD + part * 16);
    uint4 qa = qr[0], qa2 = qr[1];
    int d0 = part * 16;
    float f0, f1;
    bfpair(qa.x, f0, f1);  Qt[d0+ 0][row] = f0; Qt[d0+ 1][row] = f1;
    bfpair(qa.y, f0, f1);  Qt[d0+ 2][row] = f0; Qt[d0+ 3][row] = f1;
    bfpair(qa.z, f0, f1);  Qt[d0+ 4][row] = f0; Qt[d0+ 5][row] = f1;
    bfpair(qa.w, f0, f1);  Qt[d0+ 6][row] = f0; Qt[d0+ 7][row] = f1;
    bfpair(qa2.x, f0, f1); Qt[d0+ 8][row] = f0; Qt[d0+ 9][row] = f1;
    bfpair(qa2.y, f0, f1); Qt[d0+10][row] = f0; Qt[d0+11][row] = f1;
    bfpair(qa2.z, f0, f1); Qt[d0+12][row] = f0; Qt[d0+13][row] = f1;
    bfpair(qa2.w, f0, f1); Qt[d0+14][row] = f0; Qt[d0+15][row] = f1;
  }
  float acc[4][4] = {};
  float mreg[4] = {-1e30f, -1e30f, -1e30f, -1e30f};
  float lreg[4] = {0.f, 0.f, 0.f, 0.f};
  __syncthreads();
  for (int it = 0; it < 4; ++it) {
    int lm0 = it * 64;
    {
      int jj = tid >> 2, part = tid & 3;
      int d0 = part * 16;
      const float4* kr = reinterpret_cast<const float4*>(
          kl + ((size_t)bh * NLM + lm0 + jj) * DHEAD + d0);
      float4 k0 = kr[0], k1 = kr[1], k2 = kr[2], k3 = kr[3];
      Kt[d0+ 0][jj] = k0.x; Kt[d0+ 1][jj] = k0.y; Kt[d0+ 2][jj] = k0.z; Kt[d0+ 3][jj] = k0.w;
      Kt[d0+ 4][jj] = k1.x; Kt[d0+ 5][jj] = k1.y; Kt[d0+ 6][jj] = k1.z; Kt[d0+ 7][jj] = k1.w;
      Kt[d0+ 8][jj] = k2.x; Kt[d0+ 9][jj] = k2.y; Kt[d0+10][jj] = k2.z; Kt[d0+11][jj] = k2.w;
      Kt[d0+12][jj] = k3.x; Kt[d0+13][jj] = k3.y; Kt[d0+14][jj] = k3.z; Kt[d0+15][jj] = k3.w;
      const float4* ur = reinterpret_cast<const float4*>(
          U + ((size_t)bh * NLM + lm0 + jj) * DHEAD + d0);
      float4* ud = reinterpret_cast<float4*>(&Us[jj][d0]);
      ud[0] = ur[0]; ud[1] = ur[1]; ud[2] = ur[2]; ud[3] = ur[3];
    }
    __syncthreads();
    float s[4][4] = {};
    #pragma unroll 16
    for (int dk = 0; dk < 64; ++dk) {
      float4 a4 = *reinterpret_cast<const float4*>(&Qt[dk][ty * 4]);
      float4 b4 = *reinterpret_cast<const float4*>(&Kt[dk][tx * 4]);
      s[0][0] += a4.x*b4.x; s[0][1] += a4.x*b4.y; s[0][2] += a4.x*b4.z; s[0][3] += a4.x*b4.w;
      s[1][0] += a4.y*b4.x; s[1][1] += a4.y*b4.y; s[1][2] += a4.y*b4.z; s[1][3] += a4.y*b4.w;
      s[2][0] += a4.z*b4.x; s[2][1] += a4.z*b4.y; s[2][2] += a4.z*b4.z; s[2][3] += a4.z*b4.w;
      s[3][0] += a4.w*b4.x; s[3][1] += a4.w*b4.y; s[3][2] += a4.w*b4.z; s[3][3] += a4.w*b4.w;
    }
    #pragma unroll
    for (int i = 0; i < 4; ++i) {
      float mt = fmaxf(fmaxf(s[i][0], s[i][1]), fmaxf(s[i][2], s[i][3]));
      #pragma unroll
      for (int off = 1; off < 16; off <<= 1) mt = fmaxf(mt, __shfl_xor(mt, off));
      float mnew = fmaxf(mreg[i], mt);
      float corr = __expf(mreg[i] - mnew);
      float ts = 0.f;
      #pragma unroll
      for (int j = 0; j < 4; ++j) { s[i][j] = __expf(s[i][j] - mnew); ts += s[i][j]; }
      #pragma unroll
      for (int off = 1; off < 16; off <<= 1) ts += __shfl_xor(ts, off);
      lreg[i] = lreg[i] * corr + ts;
      mreg[i] = mnew;
      acc[i][0] *= corr; acc[i][1] *= corr; acc[i][2] *= corr; acc[i][3] *= corr;
    }
    #pragma unroll
    for (int i = 0; i < 4; ++i)
      #pragma unroll
      for (int j = 0; j < 4; ++j) Pt[tx * 4 + j][ty * 4 + i] = s[i][j];
    __syncthreads();
    #pragma unroll 16
    for (int j = 0; j < 64; ++j) {
      float4 p4 = *reinterpret_cast<const float4*>(&Pt[j][ty * 4]);
      float4 v4 = *reinterpret_cast<const float4*>(&Us[j][tx * 4]);
      acc[0][0] += p4.x*v4.x; acc[0][1] += p4.x*v4.y; acc[0][2] += p4.x*v4.z; acc[0][3] += p4.x*v4.w;
      acc[1][0] += p4.y*v4.x; acc[1][1] += p4.y*v4.y; acc[1][2] += p4.y*v4.z; acc[1][3] += p4.y*v4.w;
      acc[2][0] += p4.z*v4.x; acc[2][1] += p4.z*v4.y; acc[2][2] += p4.z*v4.z; acc[2][3] += p4.z*v4.w;
      acc[3][0] += p4.w*v4.x; acc[3][1] += p4.w*v4.y; acc[3][2] += p4.w*v4.z; acc[3][3] += p4.w*v4.w;
    }
    __syncthreads();
  }
  int b = bh >> 3, h = bh & 7;
  #pragma unroll
  for (int i = 0; i < 4; ++i) {
    float inv = 1.0f / lreg[i];
    int n = n0 + ty * 4 + i;
    ushort4 o;
    o.x = f2bf(acc[i][0] * inv); o.y = f2bf(acc[i][1] * inv);
    o.z = f2bf(acc[i][2] * inv); o.w = f2bf(acc[i][3] * inv);
    *reinterpret_cast<ushort4*>(
        &outp[((size_t)(b * NSEQ + n)) * DMODEL + h * DHEAD + tx * 4]) = o;
  }
}

// ---------------- depthwise conv residual, added into bf16 out_pre ----------------
__global__ void conv_kernel(const bf16_t* __restrict__ v, const float* __restrict__ rk,
                            bf16_t* __restrict__ outp) {
  int idx = blockIdx.x * 256 + threadIdx.x;
  int d = idx & 63, h = (idx >> 6) & 7, n = (idx >> 9) & 8191, b = idx >> 22;
  const bf16_t* vb = v + ((size_t)(b * NHEADS + h) * NSEQ) * DHEAD + d;
  const float* wk = rk + h * KCONV;
  float acc = 0.f;
  #pragma unroll
  for (int tp = 0; tp < KCONV; ++tp) {
    int nn = n + tp - 16;
    if (nn >= 0 && nn < NSEQ) acc += bf2f(vb[(size_t)nn * DHEAD]) * wk[tp];
  }
  outp[idx] = f2bf(bf2f(outp[idx]) + acc);
}

extern "C" void kernel_launch(void* const* d_in, const int* in_sizes, int n_in,
                              void* d_out, int out_size, void* d_ws, size_t ws_size,
                              hipStream_t stream) {
  const float* x     = (const float*)d_in[0];
  const float* gamma = (const float*)d_in[1];
  const float* beta  = (const float*)d_in[2];
  const float* wqkv  = (const float*)d_in[3];
  const float* wout  = (const float*)d_in[4];
  const float* bout  = (const float*)d_in[5];
  const float* rk    = (const float*)d_in[6];
  float* y = (float*)d_out;

  // ---- workspace layout ----
  char* wsb = (char*)d_ws;
  bf16_t* xn = (bf16_t*)(wsb);                   // 32 MB, reused as out_pre
  bf16_t* q  = (bf16_t*)(wsb + 33554432ull);     // 32 MB
  bf16_t* k  = (bf16_t*)(wsb + 67108864ull);     // 32 MB
  bf16_t* v  = (bf16_t*)(wsb + 100663296ull);    // 32 MB
  float* a2  = (float*)(wsb + 134217728ull);     // 8 MB
  float* z   = (float*)(wsb + 142606336ull);     // 8 MB
  float* az  = (float*)(wsb + 150994944ull);     // 8 MB (dead after pinv -> Wpart)
  float* t1  = (float*)(wsb + 159383552ull);     // 8 MB (dead after pinv -> mlpart)
  float* t2  = (float*)(wsb + 167772160ull);     // 8 MB
  float* ql  = (float*)(wsb + 176160768ull);     // 2 MB
  float* kl  = (float*)(wsb + 178257920ull);     // 2 MB
  float* Wm  = (float*)(wsb + 180355072ull);     // 2 MB
  float* Um  = (float*)(wsb + 182452224ull);     // 2 MB (doubles as wqkvT early)
  unsigned int* scal = (unsigned int*)(wsb + 184549376ull);  // 8 B
  bf16_t* wqkvT = (bf16_t*)(wsb + 182452224ull); // 1.5 MB, dead before zw writes Um
  bf16_t* woutT = (bf16_t*)(wsb + 184549440ull); // 512 KB

  castT_kernel<<<3072, 256, 0, stream>>>(wqkv, wqkvT, 1536);
  castT_kernel<<<1024, 256, 0, stream>>>(wout, woutT, 512);
  ln_kernel<<<8192, 256, 0, stream>>>(x, gamma, beta, xn);
  gemm_qkv_mfma<<<dim3(256, 12), 256, 0, stream>>>(xn, wqkvT, q, k, v);
  pool_kernel<<<4096, 256, 0, stream>>>(q, k, ql, kl);
  attn2_kernel<<<dim3(256, 32), 256, 0, stream>>>(ql, kl, a2);
  zero2_kernel<<<1, 64, 0, stream>>>(scal);
  colrow_kernel<<<64, 256, 0, stream>>>(a2, scal);
  zinit_kernel<<<8192, 256, 0, stream>>>(a2, scal, z);

  float *pz = z, *paz = az, *pt1 = t1, *pt2 = t2;
  for (int it = 0; it < 6; ++it) {
    matmul256<<<dim3(16, 32), 256, 0, stream>>>(paz, a2, pz, 0.f, -1.f);   // az = a@z
    matmul256<<<dim3(16, 32), 256, 0, stream>>>(pt2, paz, paz, 7.f, 1.f);  // t2 = 7*az - az@az
    matmul256<<<dim3(16, 32), 256, 0, stream>>>(pt1, paz, pt2, 15.f, 1.f); // t1 = 15*az - az@t2
    matmul256<<<dim3(16, 32), 256, 0, stream>>>(pt2, pz, pt1, 13.f, 0.25f);// z' = .25*(13z - z@t1)
    float* tmp = pz; pz = pt2; pt2 = tmp;
  }
  float* Wpart  = az;   // 4 MB
  float* mlpart = t1;   // 128 KB

  attn3v_flash<<<dim3(2, 4, 32), 256, 0, stream>>>(ql, k, v, Wpart, mlpart);
  attn3v_combine<<<2048, 256, 0, stream>>>(Wpart, mlpart, Wm);
  zw_kernel<<<2048, 256, 0, stream>>>(pz, Wm, Um);
  attn1_flash<<<dim3(128, 32), 256, 0, stream>>>(q, kl, Um, xn /*out_pre*/);
  conv_kernel<<<65536, 256, 0, stream>>>(v, rk, xn);
  gemm_out_mfma<<<dim3(256, 4), 256, 0, stream>>>(xn, woutT, bout, x, y);
}

// Round 6
// 856.830 us; speedup vs baseline: 9.8608x; 2.0532x over previous
//
#include <hip/hip_runtime.h>
#include <math.h>

#define NB 4
#define NSEQ 8192
#define DMODEL 512
#define NHEADS 8
#define DHEAD 64
#define NLM 256
#define LTOK 32
#define NBH 32
#define KCONV 33
#define CH3 4

typedef unsigned short bf16_t;
typedef __attribute__((ext_vector_type(8))) short bf16x8;
typedef __attribute__((ext_vector_type(4))) float f32x4;

__device__ __forceinline__ float bf2f(bf16_t u) {
  return __uint_as_float(((unsigned)u) << 16);
}
__device__ __forceinline__ bf16_t f2bf(float f) {
  unsigned u = __float_as_uint(f);
  return (bf16_t)((u + 0x7fffu + ((u >> 16) & 1u)) >> 16);  // RTNE
}
__device__ __forceinline__ void bfpair(unsigned u, float& lo, float& hi) {
  lo = __uint_as_float(u << 16);
  hi = __uint_as_float(u & 0xffff0000u);
}

// ---------------- LayerNorm ----------------
__global__ __launch_bounds__(256) void ln_kernel(const float* __restrict__ x,
    const float* __restrict__ gamma, const float* __restrict__ beta,
    bf16_t* __restrict__ xn) {
  int row = blockIdx.x * 4 + (threadIdx.x >> 6);
  int lane = threadIdx.x & 63;
  const float4* xr = reinterpret_cast<const float4*>(x + (size_t)row * DMODEL);
  float4 a0 = xr[lane];
  float4 a1 = xr[lane + 64];
  float s  = a0.x + a0.y + a0.z + a0.w + a1.x + a1.y + a1.z + a1.w;
  float s2 = a0.x*a0.x + a0.y*a0.y + a0.z*a0.z + a0.w*a0.w
           + a1.x*a1.x + a1.y*a1.y + a1.z*a1.z + a1.w*a1.w;
  #pragma unroll
  for (int off = 32; off; off >>= 1) {
    s  += __shfl_down(s, off);
    s2 += __shfl_down(s2, off);
  }
  s = __shfl(s, 0); s2 = __shfl(s2, 0);
  float mu = s * (1.0f / DMODEL);
  float var = s2 * (1.0f / DMODEL) - mu * mu;
  float rs = rsqrtf(var + 1e-5f);
  const float4* g4 = reinterpret_cast<const float4*>(gamma);
  const float4* b4 = reinterpret_cast<const float4*>(beta);
  float4 g0 = g4[lane], g1 = g4[lane + 64];
  float4 bb0 = b4[lane], bb1 = b4[lane + 64];
  ushort4 o0, o1;
  o0.x = f2bf((a0.x - mu) * rs * g0.x + bb0.x);
  o0.y = f2bf((a0.y - mu) * rs * g0.y + bb0.y);
  o0.z = f2bf((a0.z - mu) * rs * g0.z + bb0.z);
  o0.w = f2bf((a0.w - mu) * rs * g0.w + bb0.w);
  o1.x = f2bf((a1.x - mu) * rs * g1.x + bb1.x);
  o1.y = f2bf((a1.y - mu) * rs * g1.y + bb1.y);
  o1.z = f2bf((a1.z - mu) * rs * g1.z + bb1.z);
  o1.w = f2bf((a1.w - mu) * rs * g1.w + bb1.w);
  ushort4* o = reinterpret_cast<ushort4*>(xn + (size_t)row * DMODEL);
  o[lane] = o0; o[lane + 64] = o1;
}

// ---------------- transpose-cast fp32 weight [512][N] -> bf16 [N][512] ----------------
__global__ void castT_kernel(const float* __restrict__ in, bf16_t* __restrict__ outp, int N) {
  int idx = blockIdx.x * 256 + threadIdx.x;
  int k = idx & 511, c = idx >> 9;
  outp[idx] = f2bf(in[(size_t)k * N + c]);
}

// ---------------- MFMA QKV GEMM ----------------
__global__ __launch_bounds__(256) void gemm_qkv_mfma(const bf16_t* __restrict__ A,
    const bf16_t* __restrict__ Bt, bf16_t* __restrict__ q, bf16_t* __restrict__ k,
    bf16_t* __restrict__ v) {
  __shared__ __align__(16) bf16_t As[128][40];
  __shared__ __align__(16) bf16_t Bs[128][40];
  int rowB = blockIdx.x * 128, colB = blockIdx.y * 128;
  int tid = threadIdx.x;
  int wave = tid >> 6, lane = tid & 63;
  int wr = (wave >> 1) * 64, wc = (wave & 1) * 64;
  int lrow = lane & 15, g = lane >> 4;
  int srow = tid >> 1, shalf = tid & 1;
  f32x4 acc[4][4] = {};
  for (int k0 = 0; k0 < DMODEL; k0 += 32) {
    {
      const uint4* ap = reinterpret_cast<const uint4*>(
          A + (size_t)(rowB + srow) * DMODEL + k0 + shalf * 16);
      uint4 a0 = ap[0], a1 = ap[1];
      *reinterpret_cast<uint4*>(&As[srow][shalf * 16]) = a0;
      *reinterpret_cast<uint4*>(&As[srow][shalf * 16 + 8]) = a1;
      const uint4* bp = reinterpret_cast<const uint4*>(
          Bt + (size_t)(colB + srow) * DMODEL + k0 + shalf * 16);
      uint4 b0 = bp[0], b1 = bp[1];
      *reinterpret_cast<uint4*>(&Bs[srow][shalf * 16]) = b0;
      *reinterpret_cast<uint4*>(&Bs[srow][shalf * 16 + 8]) = b1;
    }
    __syncthreads();
    bf16x8 af[4], bf[4];
    #pragma unroll
    for (int m = 0; m < 4; ++m)
      af[m] = *reinterpret_cast<const bf16x8*>(&As[wr + m * 16 + lrow][g * 8]);
    #pragma unroll
    for (int n = 0; n < 4; ++n)
      bf[n] = *reinterpret_cast<const bf16x8*>(&Bs[wc + n * 16 + lrow][g * 8]);
    #pragma unroll
    for (int m = 0; m < 4; ++m)
      #pragma unroll
      for (int n = 0; n < 4; ++n)
        acc[m][n] = __builtin_amdgcn_mfma_f32_16x16x32_bf16(af[m], bf[n], acc[m][n], 0, 0, 0);
    __syncthreads();
  }
  #pragma unroll
  for (int m = 0; m < 4; ++m) {
    #pragma unroll
    for (int n = 0; n < 4; ++n) {
      int col = colB + wc + n * 16 + lrow;
      int which = col >> 9, hc = col & 511, h = hc >> 6, d = hc & 63;
      bf16_t* dst = (which == 0) ? q : (which == 1 ? k : v);
      float scale = (which == 0) ? 0.125f : 1.0f;
      #pragma unroll
      for (int r = 0; r < 4; ++r) {
        int row = rowB + wr + m * 16 + g * 4 + r;
        int b = row >> 13, nn = row & 8191;
        dst[((size_t)(b * NHEADS + h) * NSEQ + nn) * DHEAD + d] = f2bf(acc[m][n][r] * scale);
      }
    }
  }
}

// ---------------- MFMA out GEMM ----------------
__global__ __launch_bounds__(256) void gemm_out_mfma(const bf16_t* __restrict__ A,
    const bf16_t* __restrict__ Bt, const float* __restrict__ bo,
    const float* __restrict__ x, float* __restrict__ y) {
  __shared__ __align__(16) bf16_t As[128][40];
  __shared__ __align__(16) bf16_t Bs[128][40];
  int rowB = blockIdx.x * 128, colB = blockIdx.y * 128;
  int tid = threadIdx.x;
  int wave = tid >> 6, lane = tid & 63;
  int wr = (wave >> 1) * 64, wc = (wave & 1) * 64;
  int lrow = lane & 15, g = lane >> 4;
  int srow = tid >> 1, shalf = tid & 1;
  f32x4 acc[4][4] = {};
  for (int k0 = 0; k0 < DMODEL; k0 += 32) {
    {
      const uint4* ap = reinterpret_cast<const uint4*>(
          A + (size_t)(rowB + srow) * DMODEL + k0 + shalf * 16);
      uint4 a0 = ap[0], a1 = ap[1];
      *reinterpret_cast<uint4*>(&As[srow][shalf * 16]) = a0;
      *reinterpret_cast<uint4*>(&As[srow][shalf * 16 + 8]) = a1;
      const uint4* bp = reinterpret_cast<const uint4*>(
          Bt + (size_t)(colB + srow) * DMODEL + k0 + shalf * 16);
      uint4 b0 = bp[0], b1 = bp[1];
      *reinterpret_cast<uint4*>(&Bs[srow][shalf * 16]) = b0;
      *reinterpret_cast<uint4*>(&Bs[srow][shalf * 16 + 8]) = b1;
    }
    __syncthreads();
    bf16x8 af[4], bf[4];
    #pragma unroll
    for (int m = 0; m < 4; ++m)
      af[m] = *reinterpret_cast<const bf16x8*>(&As[wr + m * 16 + lrow][g * 8]);
    #pragma unroll
    for (int n = 0; n < 4; ++n)
      bf[n] = *reinterpret_cast<const bf16x8*>(&Bs[wc + n * 16 + lrow][g * 8]);
    #pragma unroll
    for (int m = 0; m < 4; ++m)
      #pragma unroll
      for (int n = 0; n < 4; ++n)
        acc[m][n] = __builtin_amdgcn_mfma_f32_16x16x32_bf16(af[m], bf[n], acc[m][n], 0, 0, 0);
    __syncthreads();
  }
  #pragma unroll
  for (int m = 0; m < 4; ++m) {
    #pragma unroll
    for (int n = 0; n < 4; ++n) {
      int col = colB + wc + n * 16 + lrow;
      float bias = bo[col];
      #pragma unroll
      for (int r = 0; r < 4; ++r) {
        int row = rowB + wr + m * 16 + g * 4 + r;
        size_t off = (size_t)row * DMODEL + col;
        y[off] = x[off] + bias + acc[m][n][r];
      }
    }
  }
}

// ---------------- landmark pooling: fp32 (attn2/pinv) + bf16 (flash) ----------------
__global__ void pool_kernel(const bf16_t* __restrict__ q, const bf16_t* __restrict__ k,
                            float* __restrict__ ql, float* __restrict__ kl,
                            bf16_t* __restrict__ qlb, bf16_t* __restrict__ klb) {
  int idx = blockIdx.x * 256 + threadIdx.x;  // 2 * 524288
  const int half = NBH * NLM * DHEAD;
  const bf16_t* src = (idx < half) ? q : k;
  float* dst = (idx < half) ? ql : kl;
  bf16_t* dstb = (idx < half) ? qlb : klb;
  int i = (idx < half) ? idx : idx - half;
  int d = i & 63, m = (i >> 6) & 255, bh = i >> 14;
  const bf16_t* p = src + ((size_t)bh * NSEQ + m * LTOK) * DHEAD + d;
  float sum = 0.f;
  #pragma unroll
  for (int t = 0; t < LTOK; ++t) sum += bf2f(p[(size_t)t * DHEAD]);
  float r = sum * (1.0f / LTOK);
  dst[i] = r;
  dstb[i] = f2bf(r);
}

// ---------------- attn2 = softmax(q_l @ k_l^T) fp32 ----------------
__global__ __launch_bounds__(256) void attn2_kernel(const float* __restrict__ ql,
    const float* __restrict__ kl, float* __restrict__ a2) {
  __shared__ float qs[64];
  __shared__ float red[256];
  int bh = blockIdx.y, i = blockIdx.x, t = threadIdx.x;
  if (t < 64) qs[t] = ql[((size_t)bh * NLM + i) * DHEAD + t];
  __syncthreads();
  const float* kr = kl + ((size_t)bh * NLM + t) * DHEAD;
  float s = 0.f;
  #pragma unroll
  for (int d = 0; d < 64; ++d) s += qs[d] * kr[d];
  red[t] = s; __syncthreads();
  for (int off = 128; off; off >>= 1) { if (t < off) red[t] = fmaxf(red[t], red[t + off]); __syncthreads(); }
  float mx = red[0]; __syncthreads();
  float p = expf(s - mx);
  red[t] = p; __syncthreads();
  for (int off = 128; off; off >>= 1) { if (t < off) red[t] += red[t + off]; __syncthreads(); }
  a2[((size_t)bh * NLM + i) * NLM + t] = p / red[0];
}

__global__ void zero2_kernel(unsigned int* __restrict__ scal) {
  if (threadIdx.x < 2) scal[threadIdx.x] = 0u;
}

__global__ void colrow_kernel(const float* __restrict__ a2, unsigned int* __restrict__ scal) {
  int bh = blockIdx.x & 31, mode = blockIdx.x >> 5;
  int t = threadIdx.x;
  const float* Ab = a2 + (size_t)bh * NLM * NLM;
  float sum = 0.f;
  if (mode == 0) { for (int j = 0; j < NLM; ++j) sum += fabsf(Ab[(size_t)t * NLM + j]); }
  else           { for (int i2 = 0; i2 < NLM; ++i2) sum += fabsf(Ab[(size_t)i2 * NLM + t]); }
  __shared__ float red[256];
  red[t] = sum; __syncthreads();
  for (int off = 128; off; off >>= 1) { if (t < off) red[t] = fmaxf(red[t], red[t + off]); __syncthreads(); }
  if (t == 0) atomicMax(&scal[mode], __float_as_uint(red[0]));
}

__global__ void zinit_kernel(const float* __restrict__ a2, const unsigned int* __restrict__ scal,
                             float* __restrict__ z) {
  int idx = blockIdx.x * 256 + threadIdx.x;
  float inv = 1.0f / (__uint_as_float(scal[0]) * __uint_as_float(scal[1]));
  int j = idx & 255, i = (idx >> 8) & 255, bh = idx >> 16;
  z[idx] = a2[((size_t)bh * NLM + j) * NLM + i] * inv;
}

// ---------------- batched 256x256 matmul via split-bf16 MFMA ----------------
// C = alpha*(s*A - A@B); hi/lo decomposition keeps ~fp32 accuracy
__global__ __launch_bounds__(256) void matmul256_mfma(float* __restrict__ C,
    const float* __restrict__ A, const float* __restrict__ Bm, float s, float alpha) {
  __shared__ __align__(16) bf16_t Ah[64][72];
  __shared__ __align__(16) bf16_t Al[64][72];
  __shared__ __align__(16) bf16_t Bh[64][72];
  __shared__ __align__(16) bf16_t Bl[64][72];
  int bh = blockIdx.y;
  const float* Ab = A + (size_t)bh * NLM * NLM;
  const float* Bb = Bm + (size_t)bh * NLM * NLM;
  float* Cb = C + (size_t)bh * NLM * NLM;
  int rowB = (blockIdx.x >> 2) * 64, colB = (blockIdx.x & 3) * 64;
  int tid = threadIdx.x, w = tid >> 6, lane = tid & 63, tx = lane & 15, g = lane >> 4;
  f32x4 acc[4] = {};
  for (int k0 = 0; k0 < NLM; k0 += 64) {
    {
      int jj = tid >> 2, part = tid & 3;
      const float* ar = Ab + (size_t)(rowB + jj) * NLM + k0 + part * 16;
      #pragma unroll
      for (int e = 0; e < 16; ++e) {
        float xv = ar[e];
        unsigned u = __float_as_uint(xv);
        Ah[jj][part * 16 + e] = (bf16_t)(u >> 16);
        Al[jj][part * 16 + e] = f2bf(xv - __uint_as_float(u & 0xffff0000u));
      }
      const float* br = Bb + (size_t)(k0 + jj) * NLM + colB + part * 16;
      #pragma unroll
      for (int e = 0; e < 16; ++e) {
        float xv = br[e];
        unsigned u = __float_as_uint(xv);
        Bh[part * 16 + e][jj] = (bf16_t)(u >> 16);
        Bl[part * 16 + e][jj] = f2bf(xv - __uint_as_float(u & 0xffff0000u));
      }
    }
    __syncthreads();
    #pragma unroll
    for (int ks = 0; ks < 2; ++ks) {
      bf16x8 ah = *reinterpret_cast<const bf16x8*>(&Ah[w * 16 + tx][g * 8 + 32 * ks]);
      bf16x8 al = *reinterpret_cast<const bf16x8*>(&Al[w * 16 + tx][g * 8 + 32 * ks]);
      #pragma unroll
      for (int tn = 0; tn < 4; ++tn) {
        bf16x8 bhf = *reinterpret_cast<const bf16x8*>(&Bh[tn * 16 + tx][g * 8 + 32 * ks]);
        bf16x8 blf = *reinterpret_cast<const bf16x8*>(&Bl[tn * 16 + tx][g * 8 + 32 * ks]);
        acc[tn] = __builtin_amdgcn_mfma_f32_16x16x32_bf16(ah, bhf, acc[tn], 0, 0, 0);
        acc[tn] = __builtin_amdgcn_mfma_f32_16x16x32_bf16(ah, blf, acc[tn], 0, 0, 0);
        acc[tn] = __builtin_amdgcn_mfma_f32_16x16x32_bf16(al, bhf, acc[tn], 0, 0, 0);
      }
    }
    __syncthreads();
  }
  #pragma unroll
  for (int tn = 0; tn < 4; ++tn) {
    int c = colB + tn * 16 + tx;
    #pragma unroll
    for (int r = 0; r < 4; ++r) {
      int rr = rowB + w * 16 + g * 4 + r;
      float aij = (s != 0.0f) ? Ab[(size_t)rr * NLM + c] : 0.0f;
      Cb[(size_t)rr * NLM + c] = alpha * (s * aij - acc[tn][r]);
    }
  }
}

// ---------------- MFMA flash attn3@v: partials over CH3 chunks ----------------
__global__ __launch_bounds__(256) void attn3v_mfma(const bf16_t* __restrict__ qlb,
    const bf16_t* __restrict__ k, const bf16_t* __restrict__ v,
    float* __restrict__ Wpart, float* __restrict__ mlpart) {
  __shared__ __align__(16) bf16_t Qs[64][72];
  __shared__ __align__(16) bf16_t Ks[64][72];
  __shared__ __align__(16) bf16_t Vt[64][72];
  __shared__ __align__(16) bf16_t Ps[64][72];
  int chunk = blockIdx.x, lmt = blockIdx.y, bh = blockIdx.z;
  int tid = threadIdx.x;
  int w = tid >> 6, lane = tid & 63;
  int tx = lane & 15, g = lane >> 4;
  int lm0 = lmt * 64;
  {
    int jj = tid >> 2, part = tid & 3;
    const uint4* qr = reinterpret_cast<const uint4*>(
        qlb + ((size_t)bh * NLM + lm0 + jj) * DHEAD + part * 16);
    *reinterpret_cast<uint4*>(&Qs[jj][part * 16]) = qr[0];
    *reinterpret_cast<uint4*>(&Qs[jj][part * 16 + 8]) = qr[1];
  }
  f32x4 oacc[4] = {};
  float mreg[4] = {-1e30f, -1e30f, -1e30f, -1e30f};
  float lreg[4] = {0.f, 0.f, 0.f, 0.f};
  const bf16_t* kb = k + (size_t)bh * NSEQ * DHEAD;
  const bf16_t* vb = v + (size_t)bh * NSEQ * DHEAD;
  __syncthreads();
  for (int it = 0; it < NSEQ / (CH3 * 64); ++it) {
    int n0 = chunk * (NSEQ / CH3) + it * 64;
    {
      int jj = tid >> 2, part = tid & 3;
      const uint4* kr = reinterpret_cast<const uint4*>(kb + (size_t)(n0 + jj) * DHEAD + part * 16);
      *reinterpret_cast<uint4*>(&Ks[jj][part * 16]) = kr[0];
      *reinterpret_cast<uint4*>(&Ks[jj][part * 16 + 8]) = kr[1];
      const uint4* vr = reinterpret_cast<const uint4*>(vb + (size_t)(n0 + jj) * DHEAD + part * 16);
      uint4 va = vr[0], va2 = vr[1];
      int d0 = part * 16;
      unsigned uu0 = va.x, uu1 = va.y, uu2 = va.z, uu3 = va.w;
      unsigned uu4 = va2.x, uu5 = va2.y, uu6 = va2.z, uu7 = va2.w;
      Vt[d0+ 0][jj] = (bf16_t)(uu0 & 0xffffu); Vt[d0+ 1][jj] = (bf16_t)(uu0 >> 16);
      Vt[d0+ 2][jj] = (bf16_t)(uu1 & 0xffffu); Vt[d0+ 3][jj] = (bf16_t)(uu1 >> 16);
      Vt[d0+ 4][jj] = (bf16_t)(uu2 & 0xffffu); Vt[d0+ 5][jj] = (bf16_t)(uu2 >> 16);
      Vt[d0+ 6][jj] = (bf16_t)(uu3 & 0xffffu); Vt[d0+ 7][jj] = (bf16_t)(uu3 >> 16);
      Vt[d0+ 8][jj] = (bf16_t)(uu4 & 0xffffu); Vt[d0+ 9][jj] = (bf16_t)(uu4 >> 16);
      Vt[d0+10][jj] = (bf16_t)(uu5 & 0xffffu); Vt[d0+11][jj] = (bf16_t)(uu5 >> 16);
      Vt[d0+12][jj] = (bf16_t)(uu6 & 0xffffu); Vt[d0+13][jj] = (bf16_t)(uu6 >> 16);
      Vt[d0+14][jj] = (bf16_t)(uu7 & 0xffffu); Vt[d0+15][jj] = (bf16_t)(uu7 >> 16);
    }
    __syncthreads();
    f32x4 sacc[4] = {};
    bf16x8 aq0 = *reinterpret_cast<const bf16x8*>(&Qs[w * 16 + tx][g * 8]);
    bf16x8 aq1 = *reinterpret_cast<const bf16x8*>(&Qs[w * 16 + tx][g * 8 + 32]);
    #pragma unroll
    for (int tn = 0; tn < 4; ++tn) {
      bf16x8 bk0 = *reinterpret_cast<const bf16x8*>(&Ks[tn * 16 + tx][g * 8]);
      bf16x8 bk1 = *reinterpret_cast<const bf16x8*>(&Ks[tn * 16 + tx][g * 8 + 32]);
      sacc[tn] = __builtin_amdgcn_mfma_f32_16x16x32_bf16(aq0, bk0, sacc[tn], 0, 0, 0);
      sacc[tn] = __builtin_amdgcn_mfma_f32_16x16x32_bf16(aq1, bk1, sacc[tn], 0, 0, 0);
    }
    #pragma unroll
    for (int r = 0; r < 4; ++r) {
      float mt = fmaxf(fmaxf(sacc[0][r], sacc[1][r]), fmaxf(sacc[2][r], sacc[3][r]));
      #pragma unroll
      for (int off = 1; off < 16; off <<= 1) mt = fmaxf(mt, __shfl_xor(mt, off));
      float mnew = fmaxf(mreg[r], mt);
      float corr = __expf(mreg[r] - mnew);
      float p0 = __expf(sacc[0][r] - mnew);
      float p1 = __expf(sacc[1][r] - mnew);
      float p2 = __expf(sacc[2][r] - mnew);
      float p3 = __expf(sacc[3][r] - mnew);
      float ts = p0 + p1 + p2 + p3;
      #pragma unroll
      for (int off = 1; off < 16; off <<= 1) ts += __shfl_xor(ts, off);
      lreg[r] = lreg[r] * corr + ts;
      mreg[r] = mnew;
      oacc[0][r] *= corr; oacc[1][r] *= corr; oacc[2][r] *= corr; oacc[3][r] *= corr;
      int prow = w * 16 + g * 4 + r;
      Ps[prow][tx]      = f2bf(p0);
      Ps[prow][tx + 16] = f2bf(p1);
      Ps[prow][tx + 32] = f2bf(p2);
      Ps[prow][tx + 48] = f2bf(p3);
    }
    __syncthreads();
    bf16x8 ap0 = *reinterpret_cast<const bf16x8*>(&Ps[w * 16 + tx][g * 8]);
    bf16x8 ap1 = *reinterpret_cast<const bf16x8*>(&Ps[w * 16 + tx][g * 8 + 32]);
    #pragma unroll
    for (int td = 0; td < 4; ++td) {
      bf16x8 bv0 = *reinterpret_cast<const bf16x8*>(&Vt[td * 16 + tx][g * 8]);
      bf16x8 bv1 = *reinterpret_cast<const bf16x8*>(&Vt[td * 16 + tx][g * 8 + 32]);
      oacc[td] = __builtin_amdgcn_mfma_f32_16x16x32_bf16(ap0, bv0, oacc[td], 0, 0, 0);
      oacc[td] = __builtin_amdgcn_mfma_f32_16x16x32_bf16(ap1, bv1, oacc[td], 0, 0, 0);
    }
    __syncthreads();
  }
  #pragma unroll
  for (int r = 0; r < 4; ++r) {
    size_t ob = ((size_t)(chunk * NBH + bh) * NLM + lm0 + w * 16 + g * 4 + r);
    #pragma unroll
    for (int td = 0; td < 4; ++td)
      Wpart[ob * DHEAD + tx + 16 * td] = oacc[td][r];
    if (tx == 0) { mlpart[ob * 2] = mreg[r]; mlpart[ob * 2 + 1] = lreg[r]; }
  }
}

// combine CH3 chunks
__global__ void attn3v_combine(const float* __restrict__ Wpart,
    const float* __restrict__ mlpart, float* __restrict__ Wm) {
  int idx = blockIdx.x * 256 + threadIdx.x;  // 524288
  int d = idx & 63;
  int s0 = idx >> 6;
  const int CHS = NBH * NLM;
  float M = -1e30f;
  #pragma unroll
  for (int c = 0; c < CH3; ++c) M = fmaxf(M, mlpart[((size_t)c * CHS + s0) * 2]);
  float L = 0.f, wv = 0.f;
  #pragma unroll
  for (int c = 0; c < CH3; ++c) {
    float e = __expf(mlpart[((size_t)c * CHS + s0) * 2] - M);
    L += mlpart[((size_t)c * CHS + s0) * 2 + 1] * e;
    wv += Wpart[((size_t)c * CHS + s0) * DHEAD + d] * e;
  }
  Wm[idx] = wv / L;
}

// ---------------- U = Z @ W, bf16 out ----------------
__global__ void zw_kernel(const float* __restrict__ z, const float* __restrict__ W,
                          bf16_t* __restrict__ Ub) {
  int idx = blockIdx.x * 256 + threadIdx.x;
  int d = idx & 63, i = (idx >> 6) & 255, bh = idx >> 14;
  const float* zr = z + ((size_t)bh * NLM + i) * NLM;
  const float* Wb = W + (size_t)bh * NLM * DHEAD + d;
  float acc = 0.f;
  for (int j = 0; j < NLM; ++j) acc += zr[j] * Wb[(size_t)j * DHEAD];
  Ub[idx] = f2bf(acc);
}

// ---------------- MFMA flash attn1 ----------------
__global__ __launch_bounds__(256) void attn1_mfma(const bf16_t* __restrict__ q,
    const bf16_t* __restrict__ klb, const bf16_t* __restrict__ Ub,
    bf16_t* __restrict__ outp) {
  __shared__ __align__(16) bf16_t Qs[64][72];
  __shared__ __align__(16) bf16_t Ks[64][72];
  __shared__ __align__(16) bf16_t Vt[64][72];
  __shared__ __align__(16) bf16_t Ps[64][72];
  int nt = blockIdx.x, bh = blockIdx.y;
  int tid = threadIdx.x;
  int w = tid >> 6, lane = tid & 63;
  int tx = lane & 15, g = lane >> 4;
  int n0 = nt * 64;
  {
    int jj = tid >> 2, part = tid & 3;
    const uint4* qr = reinterpret_cast<const uint4*>(
        q + ((size_t)bh * NSEQ + n0 + jj) * DHEAD + part * 16);
    *reinterpret_cast<uint4*>(&Qs[jj][part * 16]) = qr[0];
    *reinterpret_cast<uint4*>(&Qs[jj][part * 16 + 8]) = qr[1];
  }
  f32x4 oacc[4] = {};
  float mreg[4] = {-1e30f, -1e30f, -1e30f, -1e30f};
  float lreg[4] = {0.f, 0.f, 0.f, 0.f};
  __syncthreads();
  for (int it = 0; it < 4; ++it) {
    int lm0 = it * 64;
    {
      int jj = tid >> 2, part = tid & 3;
      const uint4* kr = reinterpret_cast<const uint4*>(
          klb + ((size_t)bh * NLM + lm0 + jj) * DHEAD + part * 16);
      *reinterpret_cast<uint4*>(&Ks[jj][part * 16]) = kr[0];
      *reinterpret_cast<uint4*>(&Ks[jj][part * 16 + 8]) = kr[1];
      const uint4* vr = reinterpret_cast<const uint4*>(
          Ub + ((size_t)bh * NLM + lm0 + jj) * DHEAD + part * 16);
      uint4 va = vr[0], va2 = vr[1];
      int d0 = part * 16;
      unsigned uu0 = va.x, uu1 = va.y, uu2 = va.z, uu3 = va.w;
      unsigned uu4 = va2.x, uu5 = va2.y, uu6 = va2.z, uu7 = va2.w;
      Vt[d0+ 0][jj] = (bf16_t)(uu0 & 0xffffu); Vt[d0+ 1][jj] = (bf16_t)(uu0 >> 16);
      Vt[d0+ 2][jj] = (bf16_t)(uu1 & 0xffffu); Vt[d0+ 3][jj] = (bf16_t)(uu1 >> 16);
      Vt[d0+ 4][jj] = (bf16_t)(uu2 & 0xffffu); Vt[d0+ 5][jj] = (bf16_t)(uu2 >> 16);
      Vt[d0+ 6][jj] = (bf16_t)(uu3 & 0xffffu); Vt[d0+ 7][jj] = (bf16_t)(uu3 >> 16);
      Vt[d0+ 8][jj] = (bf16_t)(uu4 & 0xffffu); Vt[d0+ 9][jj] = (bf16_t)(uu4 >> 16);
      Vt[d0+10][jj] = (bf16_t)(uu5 & 0xffffu); Vt[d0+11][jj] = (bf16_t)(uu5 >> 16);
      Vt[d0+12][jj] = (bf16_t)(uu6 & 0xffffu); Vt[d0+13][jj] = (bf16_t)(uu6 >> 16);
      Vt[d0+14][jj] = (bf16_t)(uu7 & 0xffffu); Vt[d0+15][jj] = (bf16_t)(uu7 >> 16);
    }
    __syncthreads();
    f32x4 sacc[4] = {};
    bf16x8 aq0 = *reinterpret_cast<const bf16x8*>(&Qs[w * 16 + tx][g * 8]);
    bf16x8 aq1 = *reinterpret_cast<const bf16x8*>(&Qs[w * 16 + tx][g * 8 + 32]);
    #pragma unroll
    for (int tn = 0; tn < 4; ++tn) {
      bf16x8 bk0 = *reinterpret_cast<const bf16x8*>(&Ks[tn * 16 + tx][g * 8]);
      bf16x8 bk1 = *reinterpret_cast<const bf16x8*>(&Ks[tn * 16 + tx][g * 8 + 32]);
      sacc[tn] = __builtin_amdgcn_mfma_f32_16x16x32_bf16(aq0, bk0, sacc[tn], 0, 0, 0);
      sacc[tn] = __builtin_amdgcn_mfma_f32_16x16x32_bf16(aq1, bk1, sacc[tn], 0, 0, 0);
    }
    #pragma unroll
    for (int r = 0; r < 4; ++r) {
      float mt = fmaxf(fmaxf(sacc[0][r], sacc[1][r]), fmaxf(sacc[2][r], sacc[3][r]));
      #pragma unroll
      for (int off = 1; off < 16; off <<= 1) mt = fmaxf(mt, __shfl_xor(mt, off));
      float mnew = fmaxf(mreg[r], mt);
      float corr = __expf(mreg[r] - mnew);
      float p0 = __expf(sacc[0][r] - mnew);
      float p1 = __expf(sacc[1][r] - mnew);
      float p2 = __expf(sacc[2][r] - mnew);
      float p3 = __expf(sacc[3][r] - mnew);
      float ts = p0 + p1 + p2 + p3;
      #pragma unroll
      for (int off = 1; off < 16; off <<= 1) ts += __shfl_xor(ts, off);
      lreg[r] = lreg[r] * corr + ts;
      mreg[r] = mnew;
      oacc[0][r] *= corr; oacc[1][r] *= corr; oacc[2][r] *= corr; oacc[3][r] *= corr;
      int prow = w * 16 + g * 4 + r;
      Ps[prow][tx]      = f2bf(p0);
      Ps[prow][tx + 16] = f2bf(p1);
      Ps[prow][tx + 32] = f2bf(p2);
      Ps[prow][tx + 48] = f2bf(p3);
    }
    __syncthreads();
    bf16x8 ap0 = *reinterpret_cast<const bf16x8*>(&Ps[w * 16 + tx][g * 8]);
    bf16x8 ap1 = *reinterpret_cast<const bf16x8*>(&Ps[w * 16 + tx][g * 8 + 32]);
    #pragma unroll
    for (int td = 0; td < 4; ++td) {
      bf16x8 bv0 = *reinterpret_cast<const bf16x8*>(&Vt[td * 16 + tx][g * 8]);
      bf16x8 bv1 = *reinterpret_cast<const bf16x8*>(&Vt[td * 16 + tx][g * 8 + 32]);
      oacc[td] = __builtin_amdgcn_mfma_f32_16x16x32_bf16(ap0, bv0, oacc[td], 0, 0, 0);
      oacc[td] = __builtin_amdgcn_mfma_f32_16x16x32_bf16(ap1, bv1, oacc[td], 0, 0, 0);
    }
    __syncthreads();
  }
  int b = bh >> 3, h = bh & 7;
  #pragma unroll
  for (int r = 0; r < 4; ++r) {
    float inv = 1.0f / lreg[r];
    int n = n0 + w * 16 + g * 4 + r;
    #pragma unroll
    for (int td = 0; td < 4; ++td)
      outp[((size_t)(b * NSEQ + n)) * DMODEL + h * DHEAD + tx + 16 * td] =
          f2bf(oacc[td][r] * inv);
  }
}

// ---------------- depthwise conv residual, 8-wide ----------------
__global__ void conv_kernel(const bf16_t* __restrict__ v, const float* __restrict__ rk,
                            bf16_t* __restrict__ outp) {
  int t = blockIdx.x * 256 + threadIdx.x;  // 2097152
  int d8 = t & 7, h = (t >> 3) & 7, n = (t >> 6) & 8191, b = t >> 19;
  const bf16_t* vb = v + ((size_t)(b * NHEADS + h) * NSEQ) * DHEAD + d8 * 8;
  const float* wk = rk + h * KCONV;
  float a0 = 0.f, a1 = 0.f, a2 = 0.f, a3 = 0.f, a4 = 0.f, a5 = 0.f, a6 = 0.f, a7 = 0.f;
  #pragma unroll
  for (int tp = 0; tp < KCONV; ++tp) {
    int nn = n + tp - 16;
    if (nn < 0 || nn >= NSEQ) continue;
    uint4 vv = *reinterpret_cast<const uint4*>(vb + (size_t)nn * DHEAD);
    float wgt = wk[tp];
    float lo, hi;
    bfpair(vv.x, lo, hi); a0 += lo * wgt; a1 += hi * wgt;
    bfpair(vv.y, lo, hi); a2 += lo * wgt; a3 += hi * wgt;
    bfpair(vv.z, lo, hi); a4 += lo * wgt; a5 += hi * wgt;
    bfpair(vv.w, lo, hi); a6 += lo * wgt; a7 += hi * wgt;
  }
  size_t ob = ((size_t)(b * NSEQ + n)) * DMODEL + h * DHEAD + d8 * 8;
  uint4 ov = *reinterpret_cast<uint4*>(outp + ob);
  float lo, hi;
  uint4 nv;
  bfpair(ov.x, lo, hi); nv.x = ((unsigned)f2bf(lo + a0)) | (((unsigned)f2bf(hi + a1)) << 16);
  bfpair(ov.y, lo, hi); nv.y = ((unsigned)f2bf(lo + a2)) | (((unsigned)f2bf(hi + a3)) << 16);
  bfpair(ov.z, lo, hi); nv.z = ((unsigned)f2bf(lo + a4)) | (((unsigned)f2bf(hi + a5)) << 16);
  bfpair(ov.w, lo, hi); nv.w = ((unsigned)f2bf(lo + a6)) | (((unsigned)f2bf(hi + a7)) << 16);
  *reinterpret_cast<uint4*>(outp + ob) = nv;
}

extern "C" void kernel_launch(void* const* d_in, const int* in_sizes, int n_in,
                              void* d_out, int out_size, void* d_ws, size_t ws_size,
                              hipStream_t stream) {
  const float* x     = (const float*)d_in[0];
  const float* gamma = (const float*)d_in[1];
  const float* beta  = (const float*)d_in[2];
  const float* wqkv  = (const float*)d_in[3];
  const float* wout  = (const float*)d_in[4];
  const float* bout  = (const float*)d_in[5];
  const float* rk    = (const float*)d_in[6];
  float* y = (float*)d_out;

  // ---- workspace layout (~187.2 MB high-water) ----
  char* wsb = (char*)d_ws;
  bf16_t* xn = (bf16_t*)(wsb);                   // 32 MB, reused as out_pre
  bf16_t* q  = (bf16_t*)(wsb + 33554432ull);     // 32 MB
  bf16_t* k  = (bf16_t*)(wsb + 67108864ull);     // 32 MB
  bf16_t* v  = (bf16_t*)(wsb + 100663296ull);    // 32 MB
  float* a2  = (float*)(wsb + 134217728ull);     // 8 MB
  float* z   = (float*)(wsb + 142606336ull);     // 8 MB
  float* az  = (float*)(wsb + 150994944ull);     // 8 MB (-> Wpart)
  float* t1  = (float*)(wsb + 159383552ull);     // 8 MB (-> mlpart)
  float* t2  = (float*)(wsb + 167772160ull);     // 8 MB
  float* ql  = (float*)(wsb + 176160768ull);     // 2 MB fp32
  float* kl  = (float*)(wsb + 178257920ull);     // 2 MB fp32
  float* Wm  = (float*)(wsb + 180355072ull);     // 2 MB
  bf16_t* Ub = (bf16_t*)(wsb + 182452224ull);    // 1 MB (slot shared with wqkvT)
  unsigned int* scal = (unsigned int*)(wsb + 184549376ull);  // 8 B
  bf16_t* wqkvT = (bf16_t*)(wsb + 182452224ull); // 1.5 MB, dead before zw writes Ub
  bf16_t* woutT = (bf16_t*)(wsb + 184549440ull); // 512 KB
  bf16_t* qlb = (bf16_t*)(wsb + 185073728ull);   // 1 MB
  bf16_t* klb = (bf16_t*)(wsb + 186122304ull);   // 1 MB

  castT_kernel<<<3072, 256, 0, stream>>>(wqkv, wqkvT, 1536);
  castT_kernel<<<1024, 256, 0, stream>>>(wout, woutT, 512);
  ln_kernel<<<8192, 256, 0, stream>>>(x, gamma, beta, xn);
  gemm_qkv_mfma<<<dim3(256, 12), 256, 0, stream>>>(xn, wqkvT, q, k, v);
  pool_kernel<<<4096, 256, 0, stream>>>(q, k, ql, kl, qlb, klb);
  attn2_kernel<<<dim3(256, 32), 256, 0, stream>>>(ql, kl, a2);
  zero2_kernel<<<1, 64, 0, stream>>>(scal);
  colrow_kernel<<<64, 256, 0, stream>>>(a2, scal);
  zinit_kernel<<<8192, 256, 0, stream>>>(a2, scal, z);

  float *pz = z, *paz = az, *pt1 = t1, *pt2 = t2;
  for (int it = 0; it < 6; ++it) {
    matmul256_mfma<<<dim3(16, 32), 256, 0, stream>>>(paz, a2, pz, 0.f, -1.f);   // az = a@z
    matmul256_mfma<<<dim3(16, 32), 256, 0, stream>>>(pt2, paz, paz, 7.f, 1.f);  // 7az - az@az
    matmul256_mfma<<<dim3(16, 32), 256, 0, stream>>>(pt1, paz, pt2, 15.f, 1.f); // 15az - az@t2
    matmul256_mfma<<<dim3(16, 32), 256, 0, stream>>>(pt2, pz, pt1, 13.f, 0.25f);// .25(13z - z@t1)
    float* tmp = pz; pz = pt2; pt2 = tmp;
  }
  float* Wpart  = az;   // CH3*32*256*64 fp32 = 8 MB
  float* mlpart = t1;   // CH3*32*256*2 fp32 = 256 KB

  attn3v_mfma<<<dim3(CH3, 4, 32), 256, 0, stream>>>(qlb, k, v, Wpart, mlpart);
  attn3v_combine<<<2048, 256, 0, stream>>>(Wpart, mlpart, Wm);
  zw_kernel<<<2048, 256, 0, stream>>>(pz, Wm, Ub);
  attn1_mfma<<<dim3(128, 32), 256, 0, stream>>>(q, klb, Ub, xn /*out_pre*/);
  conv_kernel<<<8192, 256, 0, stream>>>(v, rk, xn);
  gemm_out_mfma<<<dim3(256, 4), 256, 0, stream>>>(xn, woutT, bout, x, y);
}